// Round 12
// baseline (5013.389 us; speedup 1.0000x reference)
//
#include <hip/hip_runtime.h>
#include <hip/hip_bf16.h>
#include <hip/hip_cooperative_groups.h>

namespace cg = cooperative_groups;

#define B_ 4
#define C_ 80
#define T_ 800
#define R_ 3200   // B_*T_
#define DIN 160
#define NST 16
#define NC 16     // time chunks for parallel scan
#define LCH 50    // T_/NC

typedef const float* fp;

__device__ __forceinline__ void g2l16(const float* g, float* l) {
  __builtin_amdgcn_global_load_lds(
      (const __attribute__((address_space(1))) void*)g,
      (__attribute__((address_space(3))) void*)l,
      16, 0, 0);
}

__device__ __forceinline__ float blockSum(float v, float* sb) {
  for (int o = 32; o; o >>= 1) v += __shfl_xor(v, o);
  __syncthreads();
  if ((threadIdx.x & 63) == 0) sb[threadIdx.x >> 6] = v;
  __syncthreads();
  return sb[0] + sb[1] + sb[2] + sb[3];
}
__device__ __forceinline__ float blockMax(float v, float* sb) {
  for (int o = 32; o; o >>= 1) v = fmaxf(v, __shfl_xor(v, o));
  __syncthreads();
  if ((threadIdx.x & 63) == 0) sb[threadIdx.x >> 6] = v;
  __syncthreads();
  return fmaxf(fmaxf(sb[0], sb[1]), fmaxf(sb[2], sb[3]));
}

// ================= prep kernels (once) =================
__global__ __launch_bounds__(256) void prepw_k(fp in_proj, fp ff_w1,
    fp ln1_g, fp ln1_b, fp ln2_g, fp ln2_b, fp ff_b1,
    float* __restrict__ wp, float* __restrict__ uvb) {
  int idx = blockIdx.x * 256 + threadIdx.x;   // 0..7679
  int c = idx % 320, lm = idx / 320;
  int mat = lm & 1, l = lm >> 1;
  fp W = (mat ? ff_w1 : in_proj) + l * 25600;
  fp g = (mat ? ln2_g : ln1_g) + l * 80;
  fp b = (mat ? ln2_b : ln1_b) + l * 80;
  float* wpo = wp + lm * 25600;
  float u = 0.f, v = 0.f;
  for (int k = 0; k < 80; ++k) {
    float w = W[k * 320 + c];
    float gw = g[k] * w;
    wpo[k * 320 + c] = gw;
    u += gw;
    v += b[k] * w;
  }
  if (mat) v += ff_b1[l * 320 + c];
  uvb[lm * 640 + c] = u;
  uvb[lm * 640 + 320 + c] = v;
}

__global__ __launch_bounds__(256) void prepx_k(fp x_proj, float* __restrict__ xpt) {
  int idx = blockIdx.x * 256 + threadIdx.x;   // 12*5920 = 71040
  if (idx >= 71040) return;
  int l = idx / 5920, r = idx % 5920;
  int c = r / 160, k = r % 160;
  xpt[idx] = x_proj[l * 5920 + k * 37 + c];
}

__global__ __launch_bounds__(256) void prept_k(fp out_proj, fp ff_w2,
    float* __restrict__ wot, float* __restrict__ w2t) {
  int idx = blockIdx.x * 256 + threadIdx.x;
  if (idx < 153600) {
    int l = idx / 12800, r = idx % 12800;
    int c = r / 160, k = r % 160;
    wot[idx] = out_proj[l * 12800 + k * 80 + c];
  } else if (idx < 153600 + 307200) {
    int j = idx - 153600;
    int l = j / 25600, r = j % 25600;
    int c = r / 320, k = r % 320;
    w2t[j] = ff_w2[l * 25600 + k * 80 + c];
  }
}

__global__ __launch_bounds__(256) void cmn_k(fp feat, float* __restrict__ x) {
  int bc = blockIdx.x;
  int b = bc / C_, c = bc % C_;
  const float* f = feat + (b * C_ + c) * T_;
  __shared__ float sb[4];
  int tid = threadIdx.x;
  float v[4]; float s = 0.f;
  #pragma unroll
  for (int i = 0; i < 4; ++i) {
    int t = tid + i * 256;
    v[i] = (t < T_) ? f[t] : 0.f;
    s += v[i];
  }
  s = blockSum(s, sb);
  float mu = s * (1.f / T_);
  #pragma unroll
  for (int i = 0; i < 4; ++i) {
    int t = tid + i * 256;
    if (t < T_) x[(b * T_ + t) * C_ + c] = v[i] - mu;
  }
}

__global__ __launch_bounds__(256) void rstat_k(const float* __restrict__ in,
                                               float* __restrict__ must) {
  int row = blockIdx.x * 16 + (threadIdx.x >> 4);
  int c16 = threadIdx.x & 15;
  float s = 0.f, q = 0.f;
  #pragma unroll
  for (int m = 0; m < 5; ++m) {
    float v = in[row * 80 + c16 + 16 * m];
    s += v; q += v * v;
  }
  s += __shfl_xor(s, 1); s += __shfl_xor(s, 2);
  s += __shfl_xor(s, 4); s += __shfl_xor(s, 8);
  q += __shfl_xor(q, 1); q += __shfl_xor(q, 2);
  q += __shfl_xor(q, 4); q += __shfl_xor(q, 8);
  if (c16 == 0) {
    float mu = s * 0.0125f;
    float rs = rsqrtf(fmaxf(q * 0.0125f - mu * mu, 0.f) + 1e-5f);
    must[row * 2] = mu;
    must[row * 2 + 1] = rs;
  }
}

// ---- per-wave GEMM, K=80, TN=64; EPI 0: LN-fold (entry), 3: att1 ------------
template<int EPI>
__global__ __launch_bounds__(256, 4) void gw_k(const float* __restrict__ A,
    fp W, fp uv, const float* __restrict__ must, const float* __restrict__ extra,
    float* __restrict__ out, int N) {
  __shared__ float SL[5120 + 4 * 1280];
  int tid = threadIdx.x, wv = tid >> 6, ln = tid & 63;
  int bid = blockIdx.x;
  int c0 = (bid / 50) * 64;
  int row0 = ((bid % 50) * 4 + wv) * 16;
  for (int ch = wv; ch < 20; ch += 4) {
    int m = ch * 256 + ln * 4;
    int kr = m >> 6, cc = m & 63;
    int lo = __builtin_amdgcn_readfirstlane(ch * 256);
    g2l16(W + kr * N + c0 + cc, SL + lo);
  }
  int abase = __builtin_amdgcn_readfirstlane(5120 + wv * 1280);
  float* As = SL + 5120 + wv * 1280;
  #pragma unroll
  for (int i = 0; i < 5; ++i) {
    int m = i * 256 + ln * 4;
    int r = m / 80, kk = m - r * 80;
    g2l16(A + (row0 + r) * 80 + kk, SL + abase + i * 256);
  }
  __syncthreads();
  int rq = ln >> 4, c16 = ln & 15;
  float acc[4][4] = {};
  #pragma unroll 2
  for (int k4 = 0; k4 < 80; k4 += 4) {
    float4 a[4], w[4];
    #pragma unroll
    for (int i = 0; i < 4; ++i)
      a[i] = *(const float4*)&As[(rq * 4 + i) * 80 + k4];
    #pragma unroll
    for (int kk = 0; kk < 4; ++kk)
      w[kk] = *(const float4*)&SL[(k4 + kk) * 64 + c16 * 4];
    #pragma unroll
    for (int i = 0; i < 4; ++i) {
      acc[i][0] += a[i].x*w[0].x + a[i].y*w[1].x + a[i].z*w[2].x + a[i].w*w[3].x;
      acc[i][1] += a[i].x*w[0].y + a[i].y*w[1].y + a[i].z*w[2].y + a[i].w*w[3].y;
      acc[i][2] += a[i].x*w[0].z + a[i].y*w[1].z + a[i].z*w[2].z + a[i].w*w[3].z;
      acc[i][3] += a[i].x*w[0].w + a[i].y*w[1].w + a[i].z*w[2].w + a[i].w*w[3].w;
    }
  }
  float ua[4], va[4];
  if (EPI != 3) {
    *(float4*)ua = *(const float4*)&uv[c0 + c16 * 4];
    *(float4*)va = *(const float4*)&uv[N + c0 + c16 * 4];
  }
  #pragma unroll
  for (int i = 0; i < 4; ++i) {
    int row = row0 + rq * 4 + i;
    float mu = 0.f, rs = 1.f;
    if (EPI != 3) {
      float2 ms = *(const float2*)&must[row * 2];
      mu = ms.x; rs = ms.y;
    }
    float4 o;
    float* op = &o.x;
    #pragma unroll
    for (int j = 0; j < 4; ++j) {
      float v = acc[i][j];
      if (EPI == 3) {
        int c = c0 + c16 * 4 + j;
        v += extra[(row / T_) * 128 + c];
        v = fmaxf(v, 0.f);
        v = v * extra[512 + c] + extra[640 + c];
        v = tanhf(v);
      } else {
        v = rs * v - mu * rs * ua[j] + va[j];
      }
      op[j] = v;
    }
    *(float4*)&out[row * N + c0 + c16 * 4] = o;
  }
}

// ---- block-coop GEMM (pooling att2 only) ------------------------------------
template<int EPI, int KCH, int NKC>
__global__ __launch_bounds__(256, 4) void gc_k(const float* __restrict__ A,
    fp W, fp bias, float* __restrict__ out, int Astride) {
  constexpr int P = KCH + 4;
  __shared__ float As[16 * P];
  __shared__ float Wt[80 * P];
  int tid = threadIdx.x;
  int row0 = blockIdx.x * 16;
  int rr = tid >> 4, c16 = tid & 15;
  float acc[5] = {};
  for (int kc = 0; kc < NKC; ++kc) {
    if (kc) __syncthreads();
    #pragma unroll
    for (int i = 0; i < 16 * KCH / 256; ++i) {
      int e = tid + i * 256;
      int r = e / KCH, k = e - r * KCH;
      As[r * P + k] = A[(row0 + r) * Astride + kc * KCH + k];
    }
    #pragma unroll
    for (int i = 0; i < KCH * 80 / 256; ++i) {
      int e = tid + i * 256;
      int kr = e / 80, c = e - kr * 80;
      Wt[c * P + kr] = W[(kc * KCH + kr) * 80 + c];
    }
    __syncthreads();
    #pragma unroll 4
    for (int k4 = 0; k4 < KCH; k4 += 4) {
      float4 a = *(const float4*)&As[rr * P + k4];
      #pragma unroll
      for (int m = 0; m < 5; ++m) {
        float4 w = *(const float4*)&Wt[(c16 + 16 * m) * P + k4];
        acc[m] += a.x * w.x + a.y * w.y + a.z * w.z + a.w * w.w;
      }
    }
  }
  int row = row0 + rr;
  #pragma unroll
  for (int m = 0; m < 5; ++m) {
    int c = c16 + 16 * m;
    float v = acc[m];
    if (EPI == 4) v += bias[c];
    out[row * 80 + c] = v;
  }
}

// ================= device-phase bodies (round-10 proven code) =================
// LDS arena: 17120 floats (68.5 KB)

__device__ void cxf_dev(float* S, int bi, const float* xz, const float* cw,
                        const float* cb, const float* xptl, const float* dtw,
                        const float* dtb, float* xcf, float* xcbb,
                        float* dbc2, float* dt2) {
  float* As   = S;           // [16][164]
  float* xpT  = S + 2624;    // [37][164]
  float* dbcl = S + 8692;    // [16][40]
  int tc = bi % 50; int rem = bi / 50;
  int b = rem & 3, dir = rem >> 2;
  int t0 = tc * 16;
  int tid = threadIdx.x;
  #pragma unroll
  for (int i = 0; i < 24; ++i) {
    int e = tid + i * 256;
    if (e < 5920) {
      int c = e / 160, k = e - c * 160;
      xpT[c * 164 + k] = xptl[e];
    }
  }
  float* xco = dir ? xcbb : xcf;
  #pragma unroll
  for (int i = 0; i < 3; ++i) {
    int e = tid + i * 256;
    if (e < 640) {
      int ii = e / 40, d4 = (e - ii * 40) * 4;
      int t = t0 + ii;
      float4 acc = *(const float4*)&cb[d4];
      #pragma unroll
      for (int k = 0; k < 4; ++k) {
        int tt = t - 3 + k;
        if (tt >= 0) {
          int src = dir ? (T_ - 1 - tt) : tt;
          float4 xv = *(const float4*)&xz[(b * T_ + src) * 320 + d4];
          float4 wv = *(const float4*)&cw[k * DIN + d4];
          acc.x += wv.x * xv.x; acc.y += wv.y * xv.y;
          acc.z += wv.z * xv.z; acc.w += wv.w * xv.w;
        }
      }
      float4 o;
      o.x = acc.x / (1.f + __expf(-acc.x));
      o.y = acc.y / (1.f + __expf(-acc.y));
      o.z = acc.z / (1.f + __expf(-acc.z));
      o.w = acc.w / (1.f + __expf(-acc.w));
      *(float4*)&As[ii * 164 + d4] = o;
      *(float4*)&xco[(b * T_ + t) * DIN + d4] = o;
    }
  }
  __syncthreads();
  int rr = tid >> 4, c16 = tid & 15;
  int grow0 = dir * R_ + b * T_ + t0;
  {
    float a0 = 0.f, a1 = 0.f, a2 = 0.f;
    for (int k4 = 0; k4 < 160; k4 += 4) {
      float4 a = *(const float4*)&As[rr * 164 + k4];
      float4 w0 = *(const float4*)&xpT[c16 * 164 + k4];
      float4 w1 = *(const float4*)&xpT[(c16 + 16) * 164 + k4];
      a0 += a.x * w0.x + a.y * w0.y + a.z * w0.z + a.w * w0.w;
      a1 += a.x * w1.x + a.y * w1.y + a.z * w1.z + a.w * w1.w;
      if (c16 < 5) {
        float4 w2 = *(const float4*)&xpT[(c16 + 32) * 164 + k4];
        a2 += a.x * w2.x + a.y * w2.y + a.z * w2.z + a.w * w2.w;
      }
    }
    dbcl[rr * 40 + c16] = a0;
    dbcl[rr * 40 + c16 + 16] = a1;
    dbc2[(grow0 + rr) * 37 + c16] = a0;
    dbc2[(grow0 + rr) * 37 + c16 + 16] = a1;
    if (c16 < 5) {
      dbcl[rr * 40 + c16 + 32] = a2;
      dbc2[(grow0 + rr) * 37 + c16 + 32] = a2;
    }
  }
  __syncthreads();
  #pragma unroll
  for (int i = 0; i < 10; ++i) {
    int e = tid + i * 256;
    int ii = e / 160, d = e - ii * 160;
    float v = dtb[d];
    #pragma unroll
    for (int m = 0; m < 5; ++m) v += dbcl[ii * 40 + m] * dtw[m * DIN + d];
    v = fmaxf(v, 0.f) + __logf(1.f + __expf(-fabsf(v)));
    dt2[(grow0 + ii) * DIN + d] = v;
  }
}

__device__ void scanA_dev(float* S, int bi, const float* dt2, const float* xcf,
                          const float* xcbb, const float* dbc2, const float* A_log,
                          float* hend, float* pprod) {
  float* sdt = S; float* sdx = S + 800; float* sB = S + 1600;
  int cch = bi % NC; int rem = bi / NC;
  int dblk = rem % 10; rem /= 10;
  int b = rem % 4; int dir = rem / 4;
  int d0 = dblk * 16;
  int tid = threadIdx.x, dl = tid >> 4, n = tid & 15;
  int d = d0 + dl;
  float Areg = -__expf(A_log[d * NST + n]);
  const float* xc = dir ? xcbb : xcf;
  int rbase = dir * R_ + b * T_ + cch * LCH;
  int rloc0 = b * T_ + cch * LCH;
  for (int e = tid; e < LCH * 16; e += 256) {
    int i = e >> 4, jj = e & 15;
    int grow = rbase + i;
    float dtv = dt2[grow * DIN + d0 + jj];
    sdt[i * 16 + jj] = dtv;
    sdx[i * 16 + jj] = dtv * xc[(rloc0 + i) * DIN + d0 + jj];
    sB[i * 16 + jj]  = dbc2[grow * 37 + 5 + jj];
  }
  __syncthreads();
  float h = 0.f, dts = 0.f;
  #pragma unroll 2
  for (int i = 0; i < LCH; ++i) {
    float dtv = sdt[i * 16 + dl];
    float aa = __expf(dtv * Areg);
    h = aa * h + sdx[i * 16 + dl] * sB[i * 16 + n];
    dts += dtv;
  }
  hend[bi * 256 + tid] = h;
  pprod[bi * 256 + tid] = __expf(dts * Areg);
}

__device__ void scanC_dev(float* S, int bi, const float* dt2, const float* dbc2,
                          const float* xcf, const float* xcbb, const float* xz,
                          const float* A_log, const float* Dp,
                          const float* hend, const float* pprod, float* ygcat) {
  float* sdt = S; float* sdx = S + 800; float* sB = S + 1600;
  float* sC = S + 2400; float* sY = S + 3200;
  int cch = bi % NC; int rem = bi / NC;
  int dblk = rem % 10; rem /= 10;
  int b = rem % 4; int dir = rem / 4;
  int d0 = dblk * 16;
  int tid = threadIdx.x, dl = tid >> 4, n = tid & 15;
  int d = d0 + dl;
  float Areg = -__expf(A_log[d * NST + n]);
  const float* xc = dir ? xcbb : xcf;
  int rbase = dir * R_ + b * T_ + cch * LCH;
  int rloc0 = b * T_ + cch * LCH;
  int sbase = (bi / NC) * (NC * 256) + tid;
  float h = 0.f;
  #pragma unroll
  for (int cc = 0; cc < NC; ++cc) {
    float p = pprod[sbase + cc * 256];
    float e = hend[sbase + cc * 256];
    if (cc < cch) h = p * h + e;
  }
  for (int e = tid; e < LCH * 16; e += 256) {
    int i = e >> 4, jj = e & 15;
    int grow = rbase + i;
    float dtv = dt2[grow * DIN + d0 + jj];
    sdt[i * 16 + jj] = dtv;
    sdx[i * 16 + jj] = dtv * xc[(rloc0 + i) * DIN + d0 + jj];
    sB[i * 16 + jj]  = dbc2[grow * 37 + 5 + jj];
    sC[i * 16 + jj]  = dbc2[grow * 37 + 21 + jj];
  }
  __syncthreads();
  for (int i = 0; i < LCH; ++i) {
    float a = __expf(sdt[i * 16 + dl] * Areg);
    h = a * h + sdx[i * 16 + dl] * sB[i * 16 + n];
    float y = h * sC[i * 16 + n];
    y += __shfl_xor(y, 1);
    y += __shfl_xor(y, 2);
    y += __shfl_xor(y, 4);
    y += __shfl_xor(y, 8);
    if (n == 0) sY[i * 16 + dl] = y;
  }
  __syncthreads();
  for (int e = tid; e < LCH * 16; e += 256) {
    int i = e >> 4, jj = e & 15;
    int t = cch * LCH + i;
    int rloc = b * T_ + t;
    float xcv = xc[rloc * DIN + d0 + jj];
    int orow = dir ? (b * T_ + (T_ - 1 - t)) : rloc;
    float z = xz[orow * 320 + 160 + d0 + jj];
    float sg = 1.f / (1.f + __expf(-z));
    ygcat[orow * 320 + dir * 160 + d0 + jj] = (sY[i * 16 + jj] + xcv * Dp[d0 + jj]) * (z * sg);
  }
}

__device__ void gof_dev(float* S, int bid, const float* yg, const float* wotl,
                        const float* w1pl, const float* uv1, float* g1) {
  float* Wt = S;             // [80][164]
  float* As = S + 13120;     // [16][164]
  float* sl = S + 15744;     // [16][84]
  float* ss = S + 17088;     // [32]
  int tid = threadIdx.x, row0 = bid * 16, rr = tid >> 4, c16 = tid & 15;
  #pragma unroll
  for (int i = 0; i < 10; ++i) {
    int e = tid + i * 256; int r = e / 160, k = e - r * 160;
    As[r * 164 + k] = yg[(row0 + r) * 320 + k] + yg[(row0 + r) * 320 + 160 + k];
  }
  #pragma unroll
  for (int i = 0; i < 50; ++i) {
    int e = tid + i * 256; int c = e / 160, k = e - c * 160;
    Wt[c * 164 + k] = wotl[e];
  }
  __syncthreads();
  {
    float acc[5] = {};
    #pragma unroll 4
    for (int k4 = 0; k4 < 160; k4 += 4) {
      float4 a = *(const float4*)&As[rr * 164 + k4];
      #pragma unroll
      for (int m = 0; m < 5; ++m) {
        float4 w = *(const float4*)&Wt[(c16 + 16 * m) * 164 + k4];
        acc[m] += a.x * w.x + a.y * w.y + a.z * w.z + a.w * w.w;
      }
    }
    float s = 0.f, q = 0.f;
    #pragma unroll
    for (int m = 0; m < 5; ++m) {
      float v = acc[m];
      sl[rr * 84 + c16 + 16 * m] = v;
      s += v; q += v * v;
    }
    s += __shfl_xor(s, 1); s += __shfl_xor(s, 2);
    s += __shfl_xor(s, 4); s += __shfl_xor(s, 8);
    q += __shfl_xor(q, 1); q += __shfl_xor(q, 2);
    q += __shfl_xor(q, 4); q += __shfl_xor(q, 8);
    if (c16 == 0) {
      float mu = s * 0.0125f;
      ss[rr * 2] = mu;
      ss[rr * 2 + 1] = rsqrtf(fmaxf(q * 0.0125f - mu * mu, 0.f) + 1e-5f);
    }
  }
  for (int h = 0; h < 2; ++h) {
    __syncthreads();
    #pragma unroll
    for (int i = 0; i < 50; ++i) {
      int e = tid + i * 256; int kr = e / 160, c = e - kr * 160;
      Wt[kr * 164 + c] = w1pl[kr * 320 + h * 160 + c];
    }
    __syncthreads();
    float mu = ss[rr * 2], rs = ss[rr * 2 + 1];
    float a2[10] = {};
    for (int k = 0; k < 80; k += 4) {
      float4 av = *(const float4*)&sl[rr * 84 + k];
      #pragma unroll
      for (int m = 0; m < 10; ++m) {
        int c = c16 + 16 * m;
        a2[m] += av.x * Wt[k * 164 + c] + av.y * Wt[(k + 1) * 164 + c]
               + av.z * Wt[(k + 2) * 164 + c] + av.w * Wt[(k + 3) * 164 + c];
      }
    }
    #pragma unroll
    for (int m = 0; m < 10; ++m) {
      int c = h * 160 + c16 + 16 * m;
      float v = rs * a2[m] - mu * rs * uv1[c] + uv1[320 + c];
      v = 0.5f * v * (1.f + erff(v * 0.70710678118f));
      g1[(row0 + rr) * 320 + c] = v;
    }
  }
}

__device__ void gfi_dev(float* S, int bid, const float* g1, const float* w2tl,
                        const float* fb2, float* x, const float* wpn,
                        const float* uvn, float* xz, int last) {
  float* Wt = S;             // [80][164]
  float* As = S + 13120;     // [16][164]
  float* xn = S + 15744;     // [16][84]
  float* ss = S + 17088;     // [32]
  int tid = threadIdx.x, row0 = bid * 16, rr = tid >> 4, c16 = tid & 15;
  float acc2[5] = {};
  for (int kc = 0; kc < 2; ++kc) {
    if (kc) __syncthreads();
    #pragma unroll
    for (int i = 0; i < 10; ++i) {
      int e = tid + i * 256; int r = e / 160, k = e - r * 160;
      As[r * 164 + k] = g1[(row0 + r) * 320 + kc * 160 + k];
    }
    #pragma unroll
    for (int i = 0; i < 50; ++i) {
      int e = tid + i * 256; int c = e / 160, k = e - c * 160;
      Wt[c * 164 + k] = w2tl[c * 320 + kc * 160 + k];
    }
    __syncthreads();
    #pragma unroll 4
    for (int k4 = 0; k4 < 160; k4 += 4) {
      float4 a = *(const float4*)&As[rr * 164 + k4];
      #pragma unroll
      for (int m = 0; m < 5; ++m) {
        float4 w = *(const float4*)&Wt[(c16 + 16 * m) * 164 + k4];
        acc2[m] += a.x * w.x + a.y * w.y + a.z * w.z + a.w * w.w;
      }
    }
  }
  {
    float s = 0.f, q = 0.f;
    #pragma unroll
    for (int m = 0; m < 5; ++m) {
      int c = c16 + 16 * m;
      float v = acc2[m] + fb2[c] + x[(row0 + rr) * 80 + c];
      x[(row0 + rr) * 80 + c] = v;
      xn[rr * 84 + c] = v;
      s += v; q += v * v;
    }
    if (!last) {
      s += __shfl_xor(s, 1); s += __shfl_xor(s, 2);
      s += __shfl_xor(s, 4); s += __shfl_xor(s, 8);
      q += __shfl_xor(q, 1); q += __shfl_xor(q, 2);
      q += __shfl_xor(q, 4); q += __shfl_xor(q, 8);
      if (c16 == 0) {
        float mu = s * 0.0125f;
        ss[rr * 2] = mu;
        ss[rr * 2 + 1] = rsqrtf(fmaxf(q * 0.0125f - mu * mu, 0.f) + 1e-5f);
      }
    }
  }
  if (!last) {
    for (int h = 0; h < 2; ++h) {
      __syncthreads();
      #pragma unroll
      for (int i = 0; i < 50; ++i) {
        int e = tid + i * 256; int kr = e / 160, c = e - kr * 160;
        Wt[kr * 164 + c] = wpn[kr * 320 + h * 160 + c];
      }
      __syncthreads();
      float mu = ss[rr * 2], rs = ss[rr * 2 + 1];
      float a3[10] = {};
      for (int k = 0; k < 80; k += 4) {
        float4 av = *(const float4*)&xn[rr * 84 + k];
        #pragma unroll
        for (int m = 0; m < 10; ++m) {
          int c = c16 + 16 * m;
          a3[m] += av.x * Wt[k * 164 + c] + av.y * Wt[(k + 1) * 164 + c]
                 + av.z * Wt[(k + 2) * 164 + c] + av.w * Wt[(k + 3) * 164 + c];
        }
      }
      #pragma unroll
      for (int m = 0; m < 10; ++m) {
        int c = h * 160 + c16 + 16 * m;
        xz[(row0 + rr) * 320 + c] = rs * a3[m] - mu * rs * uvn[c] + uvn[320 + c];
      }
    }
  }
}

// ================= mega kernel (cooperative) =================
struct MA {
  const float *xpt, *conv_w, *conv_b, *dt_w, *dt_b, *A_log, *Dp;
  const float *wp, *uvb, *wot, *w2t, *ff_b2;
  float *x, *xz, *xcf, *xcb, *dbc2, *dt2, *hend, *pprod, *ygcat;
};

__global__ __launch_bounds__(256, 2) void mega_k(MA a) {
  __shared__ float S[17120];
  cg::grid_group gg = cg::this_grid();
  int bid = blockIdx.x;
  for (int l = 0; l < 12; ++l) {
    cxf_dev(S, bid, a.xz, a.conv_w + l * 640, a.conv_b + l * 160,
            a.xpt + l * 5920, a.dt_w + l * 800, a.dt_b + l * 160,
            a.xcf, a.xcb, a.dbc2, a.dt2);
    gg.sync();
    for (int u = bid; u < 1280; u += 400) {
      scanA_dev(S, u, a.dt2, a.xcf, a.xcb, a.dbc2, a.A_log + l * 2560,
                a.hend, a.pprod);
      __syncthreads();
    }
    gg.sync();
    for (int u = bid; u < 1280; u += 400) {
      scanC_dev(S, u, a.dt2, a.dbc2, a.xcf, a.xcb, a.xz, a.A_log + l * 2560,
                a.Dp + l * 160, a.hend, a.pprod, a.ygcat);
      __syncthreads();
    }
    gg.sync();
    if (bid < 200) {
      gof_dev(S, bid, a.ygcat, a.wot + l * 12800, a.wp + (2 * l + 1) * 25600,
              a.uvb + (2 * l + 1) * 640, a.xz);
      __syncthreads();
      int nl = (l < 11) ? (2 * l + 2) : 0;
      gfi_dev(S, bid, a.xz, a.w2t + l * 25600, a.ff_b2 + l * 80, a.x,
              a.wp + nl * 25600, a.uvb + nl * 640, a.xz, l == 11);
    }
    gg.sync();
  }
}

// ================= fallback wrappers (round-10 dispatch path) =================
__global__ __launch_bounds__(256, 2) void cxf_g(const float* xz, fp cw, fp cb,
    fp xptl, fp dtw, fp dtb, float* xcf, float* xcb, float* dbc2, float* dt2) {
  __shared__ float S[9332];
  cxf_dev(S, blockIdx.x, xz, cw, cb, xptl, dtw, dtb, xcf, xcb, dbc2, dt2);
}
__global__ __launch_bounds__(256, 2) void scanA_g(const float* dt2, const float* xcf,
    const float* xcb, const float* dbc2, fp A_log, float* hend, float* pprod) {
  __shared__ float S[2400];
  scanA_dev(S, blockIdx.x, dt2, xcf, xcb, dbc2, A_log, hend, pprod);
}
__global__ __launch_bounds__(256, 2) void scanC_g(const float* dt2, const float* dbc2,
    const float* xcf, const float* xcb, const float* xz, fp A_log, fp Dp,
    const float* hend, const float* pprod, float* ygcat) {
  __shared__ float S[4000];
  scanC_dev(S, blockIdx.x, dt2, dbc2, xcf, xcb, xz, A_log, Dp, hend, pprod, ygcat);
}
__global__ __launch_bounds__(256, 2) void gof_g(const float* yg, fp wotl, fp w1pl,
    fp uv1, float* g1) {
  __shared__ float S[17120];
  gof_dev(S, blockIdx.x, yg, wotl, w1pl, uv1, g1);
}
__global__ __launch_bounds__(256, 2) void gfi_g(const float* g1, fp w2tl, fp fb2,
    float* x, fp wpn, fp uvn, float* xz, int last) {
  __shared__ float S[17120];
  gfi_dev(S, blockIdx.x, g1, w2tl, fb2, x, wpn, uvn, xz, last);
}

// ================= tail kernels =================
__global__ __launch_bounds__(256) void stats_k(const float* __restrict__ x,
                                               float* __restrict__ meanv, float* __restrict__ stdv) {
  int bc = blockIdx.x; int b = bc / C_, c = bc % C_;
  __shared__ float sb[4];
  int tid = threadIdx.x;
  float v[4]; float s = 0.f;
  #pragma unroll
  for (int i = 0; i < 4; ++i) {
    int t = tid + i * 256;
    v[i] = (t < T_) ? x[(b * T_ + t) * C_ + c] : 0.f;
    s += v[i];
  }
  s = blockSum(s, sb);
  float mu = s * (1.f / T_);
  float q = 0.f;
  #pragma unroll
  for (int i = 0; i < 4; ++i) {
    int t = tid + i * 256;
    if (t < T_) { float dd = v[i] - mu; q += dd * dd; }
  }
  q = blockSum(q, sb);
  if (tid == 0) { meanv[bc] = mu; stdv[bc] = sqrtf(fmaxf(q * (1.f / T_), 1e-12f)); }
}

__global__ __launch_bounds__(256) void prep_k(const float* __restrict__ meanv,
    const float* __restrict__ stdv, fp w1, fp ab1, fp g1p, fp b1p, fp m1p, fp v1p,
    float* __restrict__ pack) {
  int idx = blockIdx.x * 256 + threadIdx.x;
  if (idx < 512) {
    int b = idx / 128, dcol = idx % 128;
    float acc = ab1[dcol];
    for (int c = 0; c < C_; ++c) {
      acc += meanv[b * C_ + c] * w1[(C_ + c) * 128 + dcol];
      acc += stdv[b * C_ + c] * w1[(2 * C_ + c) * 128 + dcol];
    }
    pack[idx] = acc;
  } else if (idx < 640) {
    int dcol = idx - 512;
    float kv = g1p[dcol] * rsqrtf(v1p[dcol] + 1e-5f);
    pack[512 + dcol] = kv;
    pack[640 + dcol] = b1p[dcol] - m1p[dcol] * kv;
  }
}

__global__ __launch_bounds__(256) void pool_k(const float* __restrict__ x,
    const float* __restrict__ scores, fp g2, fp b2, fp m2, fp v2,
    float* __restrict__ pooledn) {
  int bc = blockIdx.x; int b = bc / C_, c = bc % C_;
  __shared__ float sb[4];
  int tid = threadIdx.x;
  float sv[4], xv[4];
  float mx = -1e30f;
  #pragma unroll
  for (int i = 0; i < 4; ++i) {
    int t = tid + i * 256;
    if (t < T_) { sv[i] = scores[(b * T_ + t) * C_ + c]; xv[i] = x[(b * T_ + t) * C_ + c]; }
    else { sv[i] = -1e30f; xv[i] = 0.f; }
    mx = fmaxf(mx, sv[i]);
  }
  mx = blockMax(mx, sb);
  float se = 0.f, sx = 0.f, sxx = 0.f;
  #pragma unroll
  for (int i = 0; i < 4; ++i) {
    float e = expf(sv[i] - mx);
    se += e; sx += e * xv[i]; sxx += e * xv[i] * xv[i];
  }
  se = blockSum(se, sb);
  sx = blockSum(sx, sb);
  sxx = blockSum(sxx, sb);
  if (tid == 0) {
    float mu = sx / se;
    float sg = sqrtf(fmaxf(sxx / se - mu * mu, 1e-12f));
    int j0 = c, j1 = C_ + c;
    pooledn[b * 160 + j0] = (mu - m2[j0]) * rsqrtf(v2[j0] + 1e-5f) * g2[j0] + b2[j0];
    pooledn[b * 160 + j1] = (sg - m2[j1]) * rsqrtf(v2[j1] + 1e-5f) * g2[j1] + b2[j1];
  }
}

__global__ __launch_bounds__(256) void fc_k(const float* __restrict__ pooledn, fp fw, fp fb,
                                            float* __restrict__ out) {
  int idx = blockIdx.x * 256 + threadIdx.x;
  if (idx >= 4 * 192) return;
  int b = idx / 192, e = idx % 192;
  float acc = fb[e];
  for (int i = 0; i < 160; ++i) acc += pooledn[b * 160 + i] * fw[i * 192 + e];
  out[idx] = acc;
}

extern "C" void kernel_launch(void* const* d_in, const int* in_sizes, int n_in,
                              void* d_out, int out_size, void* d_ws, size_t ws_size,
                              hipStream_t stream) {
  fp feat   = (fp)d_in[0];
  fp ln1_g  = (fp)d_in[1];  fp ln1_b  = (fp)d_in[2];
  fp in_proj= (fp)d_in[3];
  fp conv_w = (fp)d_in[4];  fp conv_b = (fp)d_in[5];
  fp x_proj = (fp)d_in[6];
  fp dt_w   = (fp)d_in[7];  fp dt_b   = (fp)d_in[8];
  fp A_log  = (fp)d_in[9];  fp Dp     = (fp)d_in[10];
  fp out_proj=(fp)d_in[11];
  fp ln2_g  = (fp)d_in[12]; fp ln2_b  = (fp)d_in[13];
  fp ff_w1  = (fp)d_in[14]; fp ff_b1  = (fp)d_in[15];
  fp ff_w2  = (fp)d_in[16]; fp ff_b2  = (fp)d_in[17];
  fp att_w1 = (fp)d_in[18]; fp att_b1 = (fp)d_in[19];
  fp bn1_g  = (fp)d_in[20]; fp bn1_b  = (fp)d_in[21];
  fp bn1_m  = (fp)d_in[22]; fp bn1_v  = (fp)d_in[23];
  fp att_w2 = (fp)d_in[24]; fp att_b2 = (fp)d_in[25];
  fp bn2_g  = (fp)d_in[26]; fp bn2_b  = (fp)d_in[27];
  fp bn2_m  = (fp)d_in[28]; fp bn2_v  = (fp)d_in[29];
  fp fc_w   = (fp)d_in[30]; fp fc_b   = (fp)d_in[31];

  float* ws   = (float*)d_ws;
  float* x    = ws;               // 256000
  float* xz   = ws + 256000;      // 1024000
  float* xcf  = ws + 1280000;     // 512000
  float* xcb  = ws + 1792000;     // 512000
  float* dbc2 = ws + 2304000;     // 236800
  float* dt2  = ws + 2540800;     // 1024000
  float* hend = ws + 3564800;     // 327680
  float* pprod= ws + 3892480;     // 327680
  float* ygcat= ws + 4220160;     // 1024000
  float* meanv= ws + 5244160;     // 320
  float* stdv = ws + 5244480;     // 320
  float* pack = ws + 5244800;     // 768
  float* pooledn = ws + 5245568;  // 640
  float* wp   = ws + 5246208;     // 614400
  float* uvb  = ws + 5860608;     // 15360
  float* mst_x= ws + 5875968;     // 6400
  float* xpt  = ws + 5882368;     // 71040
  float* wot  = ws + 5953408;     // 153600
  float* w2t  = ws + 6107008;     // 307200  (end 6414208 = 25.7 MiB)
  float* a1b  = hend;             // alias: pooling only
  float* sc   = dt2;              // alias: pooling only

  prepw_k<<<30, 256, 0, stream>>>(in_proj, ff_w1, ln1_g, ln1_b, ln2_g, ln2_b,
                                  ff_b1, wp, uvb);
  prepx_k<<<278, 256, 0, stream>>>(x_proj, xpt);
  prept_k<<<1800, 256, 0, stream>>>(out_proj, ff_w2, wot, w2t);
  cmn_k<<<320, 256, 0, stream>>>(feat, x);
  rstat_k<<<200, 256, 0, stream>>>(x, mst_x);
  gw_k<0><<<250, 256, 0, stream>>>(x, wp, uvb, mst_x, nullptr, xz, 320);

  MA ma;
  ma.xpt = xpt; ma.conv_w = conv_w; ma.conv_b = conv_b;
  ma.dt_w = dt_w; ma.dt_b = dt_b; ma.A_log = A_log; ma.Dp = Dp;
  ma.wp = wp; ma.uvb = uvb; ma.wot = wot; ma.w2t = w2t; ma.ff_b2 = ff_b2;
  ma.x = x; ma.xz = xz; ma.xcf = xcf; ma.xcb = xcb;
  ma.dbc2 = dbc2; ma.dt2 = dt2; ma.hend = hend; ma.pprod = pprod;
  ma.ygcat = ygcat;
  void* kargs[] = { &ma };
  hipError_t err = hipLaunchCooperativeKernel((void*)mega_k, dim3(400), dim3(256),
                                              kargs, 0, stream);
  if (err != hipSuccess) {
    // fallback: proven round-10 per-phase dispatches
    for (int l = 0; l < 12; ++l) {
      cxf_g<<<400, 256, 0, stream>>>(xz, conv_w + l * 640, conv_b + l * 160,
                                     xpt + l * 5920, dt_w + l * 800, dt_b + l * 160,
                                     xcf, xcb, dbc2, dt2);
      scanA_g<<<1280, 256, 0, stream>>>(dt2, xcf, xcb, dbc2, A_log + l * 2560,
                                        hend, pprod);
      scanC_g<<<1280, 256, 0, stream>>>(dt2, dbc2, xcf, xcb, xz, A_log + l * 2560,
                                        Dp + l * 160, hend, pprod, ygcat);
      gof_g<<<200, 256, 0, stream>>>(ygcat, wot + l * 12800,
                                     wp + (2 * l + 1) * 25600,
                                     uvb + (2 * l + 1) * 640, xz);
      int nl = (l < 11) ? (2 * l + 2) : 0;
      gfi_g<<<200, 256, 0, stream>>>(xz, w2t + l * 25600, ff_b2 + l * 80, x,
                                     wp + nl * 25600, uvb + nl * 640, xz,
                                     l == 11 ? 1 : 0);
    }
  }

  stats_k<<<320, 256, 0, stream>>>(x, meanv, stdv);
  prep_k<<<3, 256, 0, stream>>>(meanv, stdv, att_w1, att_b1, bn1_g, bn1_b, bn1_m, bn1_v, pack);
  gw_k<3><<<100, 256, 0, stream>>>(x, att_w1, nullptr, nullptr, pack, a1b, 128);
  gc_k<4, 128, 1><<<200, 256, 0, stream>>>(a1b, att_w2, att_b2, sc, 128);
  pool_k<<<320, 256, 0, stream>>>(x, sc, bn2_g, bn2_b, bn2_m, bn2_v, pooledn);
  fc_k<<<3, 256, 0, stream>>>(pooledn, fc_w, fc_b, (float*)d_out);
}

// Round 13
// 1611.660 us; speedup vs baseline: 3.1107x; 3.1107x over previous
//
#include <hip/hip_runtime.h>
#include <hip/hip_bf16.h>

#define B_ 4
#define C_ 80
#define T_ 800
#define R_ 3200   // B_*T_
#define DIN 160
#define NST 16
#define NCH 50    // time chunks (16 steps each)
#define LCH 16

typedef const float* fp;

__device__ __forceinline__ void g2l16(const float* g, float* l) {
  __builtin_amdgcn_global_load_lds(
      (const __attribute__((address_space(1))) void*)g,
      (__attribute__((address_space(3))) void*)l,
      16, 0, 0);
}

__device__ __forceinline__ float blockSum(float v, float* sb) {
  for (int o = 32; o; o >>= 1) v += __shfl_xor(v, o);
  __syncthreads();
  if ((threadIdx.x & 63) == 0) sb[threadIdx.x >> 6] = v;
  __syncthreads();
  return sb[0] + sb[1] + sb[2] + sb[3];
}
__device__ __forceinline__ float blockMax(float v, float* sb) {
  for (int o = 32; o; o >>= 1) v = fmaxf(v, __shfl_xor(v, o));
  __syncthreads();
  if ((threadIdx.x & 63) == 0) sb[threadIdx.x >> 6] = v;
  __syncthreads();
  return fmaxf(fmaxf(sb[0], sb[1]), fmaxf(sb[2], sb[3]));
}

// ---- prep: W' = diag(g)W, u = colsum(W'), v = b@W (+bias), all 12 layers ----
__global__ __launch_bounds__(256) void prepw_k(fp in_proj, fp ff_w1,
    fp ln1_g, fp ln1_b, fp ln2_g, fp ln2_b, fp ff_b1,
    float* __restrict__ wp, float* __restrict__ uvb) {
  int idx = blockIdx.x * 256 + threadIdx.x;   // 0..7679
  int c = idx % 320, lm = idx / 320;
  int mat = lm & 1, l = lm >> 1;
  fp W = (mat ? ff_w1 : in_proj) + l * 25600;
  fp g = (mat ? ln2_g : ln1_g) + l * 80;
  fp b = (mat ? ln2_b : ln1_b) + l * 80;
  float* wpo = wp + lm * 25600;
  float u = 0.f, v = 0.f;
  for (int k = 0; k < 80; ++k) {
    float w = W[k * 320 + c];
    float gw = g[k] * w;
    wpo[k * 320 + c] = gw;
    u += gw;
    v += b[k] * w;
  }
  if (mat) v += ff_b1[l * 320 + c];
  uvb[lm * 640 + c] = u;
  uvb[lm * 640 + 320 + c] = v;
}

// ---- prep: transpose x_proj -> xpt[l][37][160] ------------------------------
__global__ __launch_bounds__(256) void prepx_k(fp x_proj, float* __restrict__ xpt) {
  int idx = blockIdx.x * 256 + threadIdx.x;   // 12*5920 = 71040
  if (idx >= 71040) return;
  int l = idx / 5920, r = idx % 5920;
  int c = r / 160, k = r % 160;
  xpt[idx] = x_proj[l * 5920 + k * 37 + c];
}

// ---- prep: transpose out_proj -> wot[l][80][160], ff_w2 -> w2t[l][80][320] --
__global__ __launch_bounds__(256) void prept_k(fp out_proj, fp ff_w2,
    float* __restrict__ wot, float* __restrict__ w2t) {
  int idx = blockIdx.x * 256 + threadIdx.x;
  if (idx < 153600) {
    int l = idx / 12800, r = idx % 12800;
    int c = r / 160, k = r % 160;
    wot[idx] = out_proj[l * 12800 + k * 80 + c];
  } else if (idx < 153600 + 307200) {
    int j = idx - 153600;
    int l = j / 25600, r = j % 25600;
    int c = r / 320, k = r % 320;
    w2t[j] = ff_w2[l * 25600 + k * 80 + c];
  }
}

// ---- CMN + transpose: feat [B,C,T] -> x [B*T, C] ----------------------------
__global__ __launch_bounds__(256) void cmn_k(fp feat, float* __restrict__ x) {
  int bc = blockIdx.x;
  int b = bc / C_, c = bc % C_;
  const float* f = feat + (b * C_ + c) * T_;
  __shared__ float sb[4];
  int tid = threadIdx.x;
  float v[4]; float s = 0.f;
  #pragma unroll
  for (int i = 0; i < 4; ++i) {
    int t = tid + i * 256;
    v[i] = (t < T_) ? f[t] : 0.f;
    s += v[i];
  }
  s = blockSum(s, sb);
  float mu = s * (1.f / T_);
  #pragma unroll
  for (int i = 0; i < 4; ++i) {
    int t = tid + i * 256;
    if (t < T_) x[(b * T_ + t) * C_ + c] = v[i] - mu;
  }
}

// ---- row stats (mu, rs) for LN fold (layer-0 entry only) --------------------
__global__ __launch_bounds__(256) void rstat_k(const float* __restrict__ in,
                                               float* __restrict__ must) {
  int row = blockIdx.x * 16 + (threadIdx.x >> 4);
  int c16 = threadIdx.x & 15;
  float s = 0.f, q = 0.f;
  #pragma unroll
  for (int m = 0; m < 5; ++m) {
    float v = in[row * 80 + c16 + 16 * m];
    s += v; q += v * v;
  }
  s += __shfl_xor(s, 1); s += __shfl_xor(s, 2);
  s += __shfl_xor(s, 4); s += __shfl_xor(s, 8);
  q += __shfl_xor(q, 1); q += __shfl_xor(q, 2);
  q += __shfl_xor(q, 4); q += __shfl_xor(q, 8);
  if (c16 == 0) {
    float mu = s * 0.0125f;
    float rs = rsqrtf(fmaxf(q * 0.0125f - mu * mu, 0.f) + 1e-5f);
    must[row * 2] = mu;
    must[row * 2 + 1] = rs;
  }
}

// ---- per-wave GEMM, K=80, TN=64; EPI 0: LN-fold (entry), 3: att1 ------------
template<int EPI>
__global__ __launch_bounds__(256, 4) void gw_k(const float* __restrict__ A,
    fp W, fp uv, const float* __restrict__ must, const float* __restrict__ extra,
    float* __restrict__ out, int N) {
  __shared__ float SL[5120 + 4 * 1280];
  int tid = threadIdx.x, wv = tid >> 6, ln = tid & 63;
  int bid = blockIdx.x;
  int c0 = (bid / 50) * 64;
  int row0 = ((bid % 50) * 4 + wv) * 16;
  for (int ch = wv; ch < 20; ch += 4) {
    int m = ch * 256 + ln * 4;
    int kr = m >> 6, cc = m & 63;
    int lo = __builtin_amdgcn_readfirstlane(ch * 256);
    g2l16(W + kr * N + c0 + cc, SL + lo);
  }
  int abase = __builtin_amdgcn_readfirstlane(5120 + wv * 1280);
  float* As = SL + 5120 + wv * 1280;
  #pragma unroll
  for (int i = 0; i < 5; ++i) {
    int m = i * 256 + ln * 4;
    int r = m / 80, kk = m - r * 80;
    g2l16(A + (row0 + r) * 80 + kk, SL + abase + i * 256);
  }
  __syncthreads();
  int rq = ln >> 4, c16 = ln & 15;
  float acc[4][4] = {};
  #pragma unroll 2
  for (int k4 = 0; k4 < 80; k4 += 4) {
    float4 a[4], w[4];
    #pragma unroll
    for (int i = 0; i < 4; ++i)
      a[i] = *(const float4*)&As[(rq * 4 + i) * 80 + k4];
    #pragma unroll
    for (int kk = 0; kk < 4; ++kk)
      w[kk] = *(const float4*)&SL[(k4 + kk) * 64 + c16 * 4];
    #pragma unroll
    for (int i = 0; i < 4; ++i) {
      acc[i][0] += a[i].x*w[0].x + a[i].y*w[1].x + a[i].z*w[2].x + a[i].w*w[3].x;
      acc[i][1] += a[i].x*w[0].y + a[i].y*w[1].y + a[i].z*w[2].y + a[i].w*w[3].y;
      acc[i][2] += a[i].x*w[0].z + a[i].y*w[1].z + a[i].z*w[2].z + a[i].w*w[3].z;
      acc[i][3] += a[i].x*w[0].w + a[i].y*w[1].w + a[i].z*w[2].w + a[i].w*w[3].w;
    }
  }
  float ua[4], va[4];
  if (EPI != 3) {
    *(float4*)ua = *(const float4*)&uv[c0 + c16 * 4];
    *(float4*)va = *(const float4*)&uv[N + c0 + c16 * 4];
  }
  #pragma unroll
  for (int i = 0; i < 4; ++i) {
    int row = row0 + rq * 4 + i;
    float mu = 0.f, rs = 1.f;
    if (EPI != 3) {
      float2 ms = *(const float2*)&must[row * 2];
      mu = ms.x; rs = ms.y;
    }
    float4 o;
    float* op = &o.x;
    #pragma unroll
    for (int j = 0; j < 4; ++j) {
      float v = acc[i][j];
      if (EPI == 3) {
        int c = c0 + c16 * 4 + j;
        v += extra[(row / T_) * 128 + c];
        v = fmaxf(v, 0.f);
        v = v * extra[512 + c] + extra[640 + c];
        v = tanhf(v);
      } else {
        v = rs * v - mu * rs * ua[j] + va[j];
      }
      op[j] = v;
    }
    *(float4*)&out[row * N + c0 + c16 * 4] = o;
  }
}

// ---- block-coop GEMM (pooling att2 only) ------------------------------------
template<int EPI, int KCH, int NKC>
__global__ __launch_bounds__(256, 4) void gc_k(const float* __restrict__ A,
    fp W, fp bias, float* __restrict__ out, int Astride) {
  constexpr int P = KCH + 4;
  __shared__ float As[16 * P];
  __shared__ float Wt[80 * P];
  int tid = threadIdx.x;
  int row0 = blockIdx.x * 16;
  int rr = tid >> 4, c16 = tid & 15;
  float acc[5] = {};
  for (int kc = 0; kc < NKC; ++kc) {
    if (kc) __syncthreads();
    #pragma unroll
    for (int i = 0; i < 16 * KCH / 256; ++i) {
      int e = tid + i * 256;
      int r = e / KCH, k = e - r * KCH;
      As[r * P + k] = A[(row0 + r) * Astride + kc * KCH + k];
    }
    #pragma unroll
    for (int i = 0; i < KCH * 80 / 256; ++i) {
      int e = tid + i * 256;
      int kr = e / 80, c = e - kr * 80;
      Wt[c * P + kr] = W[(kc * KCH + kr) * 80 + c];
    }
    __syncthreads();
    #pragma unroll 4
    for (int k4 = 0; k4 < KCH; k4 += 4) {
      float4 a = *(const float4*)&As[rr * P + k4];
      #pragma unroll
      for (int m = 0; m < 5; ++m) {
        float4 w = *(const float4*)&Wt[(c16 + 16 * m) * P + k4];
        acc[m] += a.x * w.x + a.y * w.y + a.z * w.z + a.w * w.w;
      }
    }
  }
  int row = row0 + rr;
  #pragma unroll
  for (int m = 0; m < 5; ++m) {
    int c = c16 + 16 * m;
    float v = acc[m];
    if (EPI == 4) v += bias[c];
    out[row * 80 + c] = v;
  }
}

// ---- cxfA: conv+SiLU + x_proj + dt+softplus + scan chunk summaries (LCH=16) -
// grid 400 = (dir*4+b)*50 + tc
__global__ __launch_bounds__(256) void cxfA_k(const float* __restrict__ xz,
    fp cw, fp cb, fp xptl, fp dtw, fp dtb, fp A_log,
    float* __restrict__ xcf, float* __restrict__ xcbb,
    float* __restrict__ dbc2, float* __restrict__ dt2,
    float* __restrict__ hend, float* __restrict__ pprod) {
  __shared__ float As[16 * 164];
  __shared__ float xpT[37 * 164];
  __shared__ float dbcl[16 * 40];
  __shared__ float dtl[16 * 164];
  int bi = blockIdx.x;
  int tc = bi % 50; int rem = bi / 50;
  int b = rem & 3, dir = rem >> 2;
  int t0 = tc * 16;
  int tid = threadIdx.x;
  #pragma unroll
  for (int i = 0; i < 24; ++i) {
    int e = tid + i * 256;
    if (e < 5920) {
      int c = e / 160, k = e - c * 160;
      xpT[c * 164 + k] = xptl[e];
    }
  }
  float* xco = dir ? xcbb : xcf;
  #pragma unroll
  for (int i = 0; i < 3; ++i) {
    int e = tid + i * 256;
    if (e < 640) {
      int ii = e / 40, d4 = (e - ii * 40) * 4;
      int t = t0 + ii;
      float4 acc = *(const float4*)&cb[d4];
      #pragma unroll
      for (int k = 0; k < 4; ++k) {
        int tt = t - 3 + k;
        if (tt >= 0) {
          int src = dir ? (T_ - 1 - tt) : tt;
          float4 xv = *(const float4*)&xz[(b * T_ + src) * 320 + d4];
          float4 wv = *(const float4*)&cw[k * DIN + d4];
          acc.x += wv.x * xv.x; acc.y += wv.y * xv.y;
          acc.z += wv.z * xv.z; acc.w += wv.w * xv.w;
        }
      }
      float4 o;
      o.x = acc.x / (1.f + __expf(-acc.x));
      o.y = acc.y / (1.f + __expf(-acc.y));
      o.z = acc.z / (1.f + __expf(-acc.z));
      o.w = acc.w / (1.f + __expf(-acc.w));
      *(float4*)&As[ii * 164 + d4] = o;
      *(float4*)&xco[(b * T_ + t) * DIN + d4] = o;
    }
  }
  __syncthreads();
  int rr = tid >> 4, c16 = tid & 15;
  int grow0 = dir * R_ + b * T_ + t0;
  {
    float a0 = 0.f, a1 = 0.f, a2 = 0.f;
    for (int k4 = 0; k4 < 160; k4 += 4) {
      float4 a = *(const float4*)&As[rr * 164 + k4];
      float4 w0 = *(const float4*)&xpT[c16 * 164 + k4];
      float4 w1 = *(const float4*)&xpT[(c16 + 16) * 164 + k4];
      a0 += a.x * w0.x + a.y * w0.y + a.z * w0.z + a.w * w0.w;
      a1 += a.x * w1.x + a.y * w1.y + a.z * w1.z + a.w * w1.w;
      if (c16 < 5) {
        float4 w2 = *(const float4*)&xpT[(c16 + 32) * 164 + k4];
        a2 += a.x * w2.x + a.y * w2.y + a.z * w2.z + a.w * w2.w;
      }
    }
    dbcl[rr * 40 + c16] = a0;
    dbcl[rr * 40 + c16 + 16] = a1;
    dbc2[(grow0 + rr) * 37 + c16] = a0;
    dbc2[(grow0 + rr) * 37 + c16 + 16] = a1;
    if (c16 < 5) {
      dbcl[rr * 40 + c16 + 32] = a2;
      dbc2[(grow0 + rr) * 37 + c16 + 32] = a2;
    }
  }
  __syncthreads();
  #pragma unroll
  for (int i = 0; i < 10; ++i) {
    int e = tid + i * 256;
    int ii = e / 160, d = e - ii * 160;
    float v = dtb[d];
    #pragma unroll
    for (int m = 0; m < 5; ++m) v += dbcl[ii * 40 + m] * dtw[m * DIN + d];
    v = fmaxf(v, 0.f) + __logf(1.f + __expf(-fabsf(v)));
    dtl[ii * 164 + d] = v;
    dt2[(grow0 + ii) * DIN + d] = v;
  }
  __syncthreads();
  // scan chunk summaries over the 16 local steps; k = dblk 0..9
  float h[10], dts[10], Ar[10];
  #pragma unroll
  for (int k = 0; k < 10; ++k) {
    Ar[k] = -__expf(A_log[k * 256 + tid]);
    h[k] = 0.f; dts[k] = 0.f;
  }
  for (int i = 0; i < 16; ++i) {
    float Bv = dbcl[i * 40 + 5 + (tid & 15)];
    #pragma unroll
    for (int k = 0; k < 10; ++k) {
      int d = k * 16 + (tid >> 4);
      float dtv = dtl[i * 164 + d];
      float a = __expf(dtv * Ar[k]);
      h[k] = a * h[k] + dtv * As[i * 164 + d] * Bv;
      dts[k] += dtv;
    }
  }
  int gb = (dir * 4 + b) * 10;
  #pragma unroll
  for (int k = 0; k < 10; ++k) {
    int idx = ((gb + k) * NCH + tc) * 256 + tid;
    hend[idx] = h[k];
    pprod[idx] = __expf(dts[k] * Ar[k]);
  }
}

// ---- scanC16: in-block prefix + recompute 16-step chunk + gated write -------
// grid 4000 = grp*50 + cc ; grp = (dir*4+b)*10 + dblk
__global__ __launch_bounds__(256) void scanC16_k(const float* __restrict__ dt2,
    const float* __restrict__ dbc2, const float* __restrict__ xcf,
    const float* __restrict__ xcbb, const float* __restrict__ xz,
    fp A_log, fp Dp, const float* __restrict__ hend,
    const float* __restrict__ pprod, float* __restrict__ ygcat) {
  __shared__ float sdt[16][16], sdx[16][16], sB[16][16], sC[16][16], sY[16][16];
  int bi = blockIdx.x;
  int cc = bi % NCH, grp = bi / NCH;
  int dblk = grp % 10; int rem = grp / 10;
  int b = rem & 3, dir = rem >> 2;
  int d0 = dblk * 16;
  int tid = threadIdx.x, i16 = tid >> 4, jj = tid & 15;
  const float* xc = dir ? xcbb : xcf;
  int t0 = cc * 16;
  {
    int grow = dir * R_ + b * T_ + t0 + i16;
    int rloc = b * T_ + t0 + i16;
    float dtv = dt2[grow * DIN + d0 + jj];
    sdt[i16][jj] = dtv;
    sdx[i16][jj] = dtv * xc[rloc * DIN + d0 + jj];
    sB[i16][jj] = dbc2[grow * 37 + 5 + jj];
    sC[i16][jj] = dbc2[grow * 37 + 21 + jj];
  }
  // in-block prefix over earlier chunk summaries (cc is block-uniform)
  int sbase = grp * NCH * 256 + tid;
  float h = 0.f;
  for (int c2 = 0; c2 < cc; ++c2)
    h = pprod[sbase + c2 * 256] * h + hend[sbase + c2 * 256];
  float Ar = -__expf(A_log[d0 * 16 + tid]);
  __syncthreads();
  int dl = i16, n = jj;
  for (int i = 0; i < 16; ++i) {
    float a = __expf(sdt[i][dl] * Ar);
    h = a * h + sdx[i][dl] * sB[i][n];
    float y = h * sC[i][n];
    y += __shfl_xor(y, 1);
    y += __shfl_xor(y, 2);
    y += __shfl_xor(y, 4);
    y += __shfl_xor(y, 8);
    if (n == 0) sY[i][dl] = y;
  }
  __syncthreads();
  {
    int t = t0 + i16;
    int rl = b * T_ + t;
    float xcv = xc[rl * DIN + d0 + jj];
    int orow = dir ? (b * T_ + (T_ - 1 - t)) : rl;
    float z = xz[orow * 320 + 160 + d0 + jj];
    float sg = 1.f / (1.f + __expf(-z));
    ygcat[orow * 320 + dir * 160 + d0 + jj] = (sY[i16][jj] + xcv * Dp[d0 + jj]) * (z * sg);
  }
}

// ---- gfu: out_proj + LN2 + ff1 + GELU + ff2 + residual + LN1 + next in_proj -
// one 16-row block; g1 lives only in LDS; 76.9 KB -> 2 blocks/CU
template<int LAST>
__global__ __launch_bounds__(256, 2) void gfu_k(const float* __restrict__ yg,
    fp wotl, fp w1pl, fp uv1, fp w2tl, fp fb2, float* __restrict__ x,
    fp wpn, fp uvn, float* __restrict__ xz) {
  __shared__ float S[19680];
  float* Wt  = S;            // 80*164 = 13120
  float* g1l = S + 13120;    // 16*324 = 5184 (first 2624 doubles as As in P1)
  float* sl  = S + 18304;    // 16*84 = 1344 (out_proj result; later xn)
  float* ss  = S + 19648;    // 32
  float* As  = g1l;
  int tid = threadIdx.x, row0 = blockIdx.x * 16, rr = tid >> 4, c16 = tid & 15;
  // P1 stage: ygcat halves summed + wot
  #pragma unroll
  for (int i = 0; i < 10; ++i) {
    int e = tid + i * 256; int r = e / 160, k = e - r * 160;
    As[r * 164 + k] = yg[(row0 + r) * 320 + k] + yg[(row0 + r) * 320 + 160 + k];
  }
  #pragma unroll
  for (int i = 0; i < 50; ++i) {
    int e = tid + i * 256; int c = e / 160, k = e - c * 160;
    Wt[c * 164 + k] = wotl[e];
  }
  __syncthreads();
  // P1: out_proj GEMM -> sl, LN2 stats -> ss
  {
    float acc[5] = {};
    #pragma unroll 4
    for (int k4 = 0; k4 < 160; k4 += 4) {
      float4 a = *(const float4*)&As[rr * 164 + k4];
      #pragma unroll
      for (int m = 0; m < 5; ++m) {
        float4 w = *(const float4*)&Wt[(c16 + 16 * m) * 164 + k4];
        acc[m] += a.x * w.x + a.y * w.y + a.z * w.z + a.w * w.w;
      }
    }
    float s = 0.f, q = 0.f;
    #pragma unroll
    for (int m = 0; m < 5; ++m) {
      float v = acc[m];
      sl[rr * 84 + c16 + 16 * m] = v;
      s += v; q += v * v;
    }
    s += __shfl_xor(s, 1); s += __shfl_xor(s, 2);
    s += __shfl_xor(s, 4); s += __shfl_xor(s, 8);
    q += __shfl_xor(q, 1); q += __shfl_xor(q, 2);
    q += __shfl_xor(q, 4); q += __shfl_xor(q, 8);
    if (c16 == 0) {
      float mu = s * 0.0125f;
      ss[rr * 2] = mu;
      ss[rr * 2 + 1] = rsqrtf(fmaxf(q * 0.0125f - mu * mu, 0.f) + 1e-5f);
    }
  }
  // P2: ff1 (+LN2 fold +GELU) -> g1l (stride 324)
  for (int h = 0; h < 2; ++h) {
    __syncthreads();
    #pragma unroll
    for (int i = 0; i < 50; ++i) {
      int e = tid + i * 256; int kr = e / 160, c = e - kr * 160;
      Wt[kr * 164 + c] = w1pl[kr * 320 + h * 160 + c];
    }
    __syncthreads();
    float mu = ss[rr * 2], rs = ss[rr * 2 + 1];
    float a2[10] = {};
    for (int k = 0; k < 80; k += 4) {
      float4 av = *(const float4*)&sl[rr * 84 + k];
      #pragma unroll
      for (int m = 0; m < 10; ++m) {
        int c = c16 + 16 * m;
        a2[m] += av.x * Wt[k * 164 + c] + av.y * Wt[(k + 1) * 164 + c]
               + av.z * Wt[(k + 2) * 164 + c] + av.w * Wt[(k + 3) * 164 + c];
      }
    }
    __syncthreads();   // As (overlapping g1l) fully dead only after P1; h=0 writes must wait for all waves' P1 reads
    #pragma unroll
    for (int m = 0; m < 10; ++m) {
      int c = h * 160 + c16 + 16 * m;
      float v = rs * a2[m] - mu * rs * uv1[c] + uv1[320 + c];
      v = 0.5f * v * (1.f + erff(v * 0.70710678118f));
      g1l[rr * 324 + c] = v;
    }
  }
  // P3: ff2 over two K halves from g1l
  float acc2[5] = {};
  for (int kc = 0; kc < 2; ++kc) {
    __syncthreads();
    #pragma unroll
    for (int i = 0; i < 50; ++i) {
      int e = tid + i * 256; int c = e / 160, k = e - c * 160;
      Wt[c * 164 + k] = w2tl[c * 320 + kc * 160 + k];
    }
    __syncthreads();
    #pragma unroll 4
    for (int k4 = 0; k4 < 160; k4 += 4) {
      float4 a = *(const float4*)&g1l[rr * 324 + kc * 160 + k4];
      #pragma unroll
      for (int m = 0; m < 5; ++m) {
        float4 w = *(const float4*)&Wt[(c16 + 16 * m) * 164 + k4];
        acc2[m] += a.x * w.x + a.y * w.y + a.z * w.z + a.w * w.w;
      }
    }
  }
  // P4: residual + x update; xn into sl; LN1 stats
  __syncthreads();
  {
    float s = 0.f, q = 0.f;
    #pragma unroll
    for (int m = 0; m < 5; ++m) {
      int c = c16 + 16 * m;
      float v = acc2[m] + fb2[c] + x[(row0 + rr) * 80 + c];
      x[(row0 + rr) * 80 + c] = v;
      sl[rr * 84 + c] = v;
      s += v; q += v * v;
    }
    if (!LAST) {
      s += __shfl_xor(s, 1); s += __shfl_xor(s, 2);
      s += __shfl_xor(s, 4); s += __shfl_xor(s, 8);
      q += __shfl_xor(q, 1); q += __shfl_xor(q, 2);
      q += __shfl_xor(q, 4); q += __shfl_xor(q, 8);
      if (c16 == 0) {
        float mu = s * 0.0125f;
        ss[rr * 2] = mu;
        ss[rr * 2 + 1] = rsqrtf(fmaxf(q * 0.0125f - mu * mu, 0.f) + 1e-5f);
      }
    }
  }
  // P5: next-layer in_proj (+LN1 fold) -> xz
  if (!LAST) {
    for (int h = 0; h < 2; ++h) {
      __syncthreads();
      #pragma unroll
      for (int i = 0; i < 50; ++i) {
        int e = tid + i * 256; int kr = e / 160, c = e - kr * 160;
        Wt[kr * 164 + c] = wpn[kr * 320 + h * 160 + c];
      }
      __syncthreads();
      float mu = ss[rr * 2], rs = ss[rr * 2 + 1];
      float a3[10] = {};
      for (int k = 0; k < 80; k += 4) {
        float4 av = *(const float4*)&sl[rr * 84 + k];
        #pragma unroll
        for (int m = 0; m < 10; ++m) {
          int c = c16 + 16 * m;
          a3[m] += av.x * Wt[k * 164 + c] + av.y * Wt[(k + 1) * 164 + c]
                 + av.z * Wt[(k + 2) * 164 + c] + av.w * Wt[(k + 3) * 164 + c];
        }
      }
      #pragma unroll
      for (int m = 0; m < 10; ++m) {
        int c = h * 160 + c16 + 16 * m;
        xz[(row0 + rr) * 320 + c] = rs * a3[m] - mu * rs * uvn[c] + uvn[320 + c];
      }
    }
  }
}

// ---- pooling: per-(b,c) mean/std over T -------------------------------------
__global__ __launch_bounds__(256) void stats_k(const float* __restrict__ x,
                                               float* __restrict__ meanv, float* __restrict__ stdv) {
  int bc = blockIdx.x; int b = bc / C_, c = bc % C_;
  __shared__ float sb[4];
  int tid = threadIdx.x;
  float v[4]; float s = 0.f;
  #pragma unroll
  for (int i = 0; i < 4; ++i) {
    int t = tid + i * 256;
    v[i] = (t < T_) ? x[(b * T_ + t) * C_ + c] : 0.f;
    s += v[i];
  }
  s = blockSum(s, sb);
  float mu = s * (1.f / T_);
  float q = 0.f;
  #pragma unroll
  for (int i = 0; i < 4; ++i) {
    int t = tid + i * 256;
    if (t < T_) { float dd = v[i] - mu; q += dd * dd; }
  }
  q = blockSum(q, sb);
  if (tid == 0) { meanv[bc] = mu; stdv[bc] = sqrtf(fmaxf(q * (1.f / T_), 1e-12f)); }
}

// ---- att1 pack --------------------------------------------------------------
__global__ __launch_bounds__(256) void prep_k(const float* __restrict__ meanv,
    const float* __restrict__ stdv, fp w1, fp ab1, fp g1p, fp b1p, fp m1p, fp v1p,
    float* __restrict__ pack) {
  int idx = blockIdx.x * 256 + threadIdx.x;
  if (idx < 512) {
    int b = idx / 128, dcol = idx % 128;
    float acc = ab1[dcol];
    for (int c = 0; c < C_; ++c) {
      acc += meanv[b * C_ + c] * w1[(C_ + c) * 128 + dcol];
      acc += stdv[b * C_ + c] * w1[(2 * C_ + c) * 128 + dcol];
    }
    pack[idx] = acc;
  } else if (idx < 640) {
    int dcol = idx - 512;
    float kv = g1p[dcol] * rsqrtf(v1p[dcol] + 1e-5f);
    pack[512 + dcol] = kv;
    pack[640 + dcol] = b1p[dcol] - m1p[dcol] * kv;
  }
}

// ---- softmax over T + weighted stats + bn2 ----------------------------------
__global__ __launch_bounds__(256) void pool_k(const float* __restrict__ x,
    const float* __restrict__ scores, fp g2, fp b2, fp m2, fp v2,
    float* __restrict__ pooledn) {
  int bc = blockIdx.x; int b = bc / C_, c = bc % C_;
  __shared__ float sb[4];
  int tid = threadIdx.x;
  float sv[4], xv[4];
  float mx = -1e30f;
  #pragma unroll
  for (int i = 0; i < 4; ++i) {
    int t = tid + i * 256;
    if (t < T_) { sv[i] = scores[(b * T_ + t) * C_ + c]; xv[i] = x[(b * T_ + t) * C_ + c]; }
    else { sv[i] = -1e30f; xv[i] = 0.f; }
    mx = fmaxf(mx, sv[i]);
  }
  mx = blockMax(mx, sb);
  float se = 0.f, sx = 0.f, sxx = 0.f;
  #pragma unroll
  for (int i = 0; i < 4; ++i) {
    float e = expf(sv[i] - mx);
    se += e; sx += e * xv[i]; sxx += e * xv[i] * xv[i];
  }
  se = blockSum(se, sb);
  sx = blockSum(sx, sb);
  sxx = blockSum(sxx, sb);
  if (tid == 0) {
    float mu = sx / se;
    float sg = sqrtf(fmaxf(sxx / se - mu * mu, 1e-12f));
    int j0 = c, j1 = C_ + c;
    pooledn[b * 160 + j0] = (mu - m2[j0]) * rsqrtf(v2[j0] + 1e-5f) * g2[j0] + b2[j0];
    pooledn[b * 160 + j1] = (sg - m2[j1]) * rsqrtf(v2[j1] + 1e-5f) * g2[j1] + b2[j1];
  }
}

// ---- final fc ---------------------------------------------------------------
__global__ __launch_bounds__(256) void fc_k(const float* __restrict__ pooledn, fp fw, fp fb,
                                            float* __restrict__ out) {
  int idx = blockIdx.x * 256 + threadIdx.x;
  if (idx >= 4 * 192) return;
  int b = idx / 192, e = idx % 192;
  float acc = fb[e];
  for (int i = 0; i < 160; ++i) acc += pooledn[b * 160 + i] * fw[i * 192 + e];
  out[idx] = acc;
}

extern "C" void kernel_launch(void* const* d_in, const int* in_sizes, int n_in,
                              void* d_out, int out_size, void* d_ws, size_t ws_size,
                              hipStream_t stream) {
  fp feat   = (fp)d_in[0];
  fp ln1_g  = (fp)d_in[1];  fp ln1_b  = (fp)d_in[2];
  fp in_proj= (fp)d_in[3];
  fp conv_w = (fp)d_in[4];  fp conv_b = (fp)d_in[5];
  fp x_proj = (fp)d_in[6];
  fp dt_w   = (fp)d_in[7];  fp dt_b   = (fp)d_in[8];
  fp A_log  = (fp)d_in[9];  fp Dp     = (fp)d_in[10];
  fp out_proj=(fp)d_in[11];
  fp ln2_g  = (fp)d_in[12]; fp ln2_b  = (fp)d_in[13];
  fp ff_w1  = (fp)d_in[14]; fp ff_b1  = (fp)d_in[15];
  fp ff_w2  = (fp)d_in[16]; fp ff_b2  = (fp)d_in[17];
  fp att_w1 = (fp)d_in[18]; fp att_b1 = (fp)d_in[19];
  fp bn1_g  = (fp)d_in[20]; fp bn1_b  = (fp)d_in[21];
  fp bn1_m  = (fp)d_in[22]; fp bn1_v  = (fp)d_in[23];
  fp att_w2 = (fp)d_in[24]; fp att_b2 = (fp)d_in[25];
  fp bn2_g  = (fp)d_in[26]; fp bn2_b  = (fp)d_in[27];
  fp bn2_m  = (fp)d_in[28]; fp bn2_v  = (fp)d_in[29];
  fp fc_w   = (fp)d_in[30]; fp fc_b   = (fp)d_in[31];

  float* ws   = (float*)d_ws;
  float* x    = ws;               // 256000
  float* xz   = ws + 256000;      // 1024000
  float* xcf  = ws + 1280000;     // 512000
  float* xcb  = ws + 1792000;     // 512000
  float* dbc2 = ws + 2304000;     // 236800
  float* dt2  = ws + 2540800;     // 1024000
  float* hend = ws + 3564800;     // 1024000
  float* pprod= ws + 4588800;     // 1024000
  float* ygcat= ws + 5612800;     // 1024000
  float* meanv= ws + 6636800;     // 320
  float* stdv = ws + 6637120;     // 320
  float* pack = ws + 6637440;     // 768
  float* pooledn = ws + 6638208;  // 640
  float* wp   = ws + 6638848;     // 614400
  float* uvb  = ws + 7253248;     // 15360
  float* mst_x= ws + 7268608;     // 6400
  float* xpt  = ws + 7275008;     // 71040
  float* wot  = ws + 7346048;     // 153600
  float* w2t  = ws + 7499648;     // 307200  (end 7806848 = 31.2 MiB)
  float* a1b  = hend;             // alias: pooling only
  float* sc   = dt2;              // alias: pooling only

  prepw_k<<<30, 256, 0, stream>>>(in_proj, ff_w1, ln1_g, ln1_b, ln2_g, ln2_b,
                                  ff_b1, wp, uvb);
  prepx_k<<<278, 256, 0, stream>>>(x_proj, xpt);
  prept_k<<<1800, 256, 0, stream>>>(out_proj, ff_w2, wot, w2t);
  cmn_k<<<320, 256, 0, stream>>>(feat, x);
  rstat_k<<<200, 256, 0, stream>>>(x, mst_x);
  gw_k<0><<<250, 256, 0, stream>>>(x, wp, uvb, mst_x, nullptr, xz, 320);

  for (int l = 0; l < 12; ++l) {
    cxfA_k<<<400, 256, 0, stream>>>(xz, conv_w + l * 640, conv_b + l * 160,
                                    xpt + l * 5920, dt_w + l * 800, dt_b + l * 160,
                                    A_log + l * 2560, xcf, xcb, dbc2, dt2,
                                    hend, pprod);
    scanC16_k<<<4000, 256, 0, stream>>>(dt2, dbc2, xcf, xcb, xz,
                                        A_log + l * 2560, Dp + l * 160,
                                        hend, pprod, ygcat);
    if (l < 11)
      gfu_k<0><<<200, 256, 0, stream>>>(ygcat, wot + l * 12800,
                                        wp + (2 * l + 1) * 25600,
                                        uvb + (2 * l + 1) * 640,
                                        w2t + l * 25600, ff_b2 + l * 80, x,
                                        wp + (2 * l + 2) * 25600,
                                        uvb + (2 * l + 2) * 640, xz);
    else
      gfu_k<1><<<200, 256, 0, stream>>>(ygcat, wot + l * 12800,
                                        wp + (2 * l + 1) * 25600,
                                        uvb + (2 * l + 1) * 640,
                                        w2t + l * 25600, ff_b2 + l * 80, x,
                                        wp, uvb, xz);
  }

  stats_k<<<320, 256, 0, stream>>>(x, meanv, stdv);
  prep_k<<<3, 256, 0, stream>>>(meanv, stdv, att_w1, att_b1, bn1_g, bn1_b, bn1_m, bn1_v, pack);
  gw_k<3><<<100, 256, 0, stream>>>(x, att_w1, nullptr, nullptr, pack, a1b, 128);
  gc_k<4, 128, 1><<<200, 256, 0, stream>>>(a1b, att_w2, att_b2, sc, 128);
  pool_k<<<320, 256, 0, stream>>>(x, sc, bn2_g, bn2_b, bn2_m, bn2_v, pooledn);
  fc_k<<<3, 256, 0, stream>>>(pooledn, fc_w, fc_b, (float*)d_out);
}

// Round 14
// 1171.586 us; speedup vs baseline: 4.2791x; 1.3756x over previous
//
#include <hip/hip_runtime.h>
#include <hip/hip_bf16.h>

#define B_ 4
#define C_ 80
#define T_ 800
#define R_ 3200   // B_*T_
#define DIN 160
#define NST 16
#define NC 16     // time chunks for parallel scan
#define LCH 50    // T_/NC

typedef const float* fp;

__device__ __forceinline__ void g2l16(const float* g, float* l) {
  __builtin_amdgcn_global_load_lds(
      (const __attribute__((address_space(1))) void*)g,
      (__attribute__((address_space(3))) void*)l,
      16, 0, 0);
}
__device__ __forceinline__ void g2l4(const float* g, float* l) {
  __builtin_amdgcn_global_load_lds(
      (const __attribute__((address_space(1))) void*)g,
      (__attribute__((address_space(3))) void*)l,
      4, 0, 0);
}

// async linear stage of NF4 float4s into LDS (dest lane-linear per wave)
template<int NF4>
__device__ __forceinline__ void stageN(float* dst, const float* src, int tid) {
  int wv = tid >> 6, ln = tid & 63;
  constexpr int NP = (NF4 + 255) / 256;
  #pragma unroll
  for (int i = 0; i < NP; ++i) {
    int cbase = i * 256 + wv * 64;
    if (cbase + ln < NF4) {
      int lo = __builtin_amdgcn_readfirstlane(cbase * 4);
      g2l16(src + (cbase + ln) * 4, dst + lo);
    }
  }
}

__device__ __forceinline__ float blockSum(float v, float* sb) {
  for (int o = 32; o; o >>= 1) v += __shfl_xor(v, o);
  __syncthreads();
  if ((threadIdx.x & 63) == 0) sb[threadIdx.x >> 6] = v;
  __syncthreads();
  return sb[0] + sb[1] + sb[2] + sb[3];
}
__device__ __forceinline__ float blockMax(float v, float* sb) {
  for (int o = 32; o; o >>= 1) v = fmaxf(v, __shfl_xor(v, o));
  __syncthreads();
  if ((threadIdx.x & 63) == 0) sb[threadIdx.x >> 6] = v;
  __syncthreads();
  return fmaxf(fmaxf(sb[0], sb[1]), fmaxf(sb[2], sb[3]));
}

// ---- prep: W' = diag(g)W, u = colsum(W'), v = b@W (+bias), all 12 layers ----
__global__ __launch_bounds__(256) void prepw_k(fp in_proj, fp ff_w1,
    fp ln1_g, fp ln1_b, fp ln2_g, fp ln2_b, fp ff_b1,
    float* __restrict__ wp, float* __restrict__ uvb) {
  int idx = blockIdx.x * 256 + threadIdx.x;   // 0..7679
  int c = idx % 320, lm = idx / 320;
  int mat = lm & 1, l = lm >> 1;
  fp W = (mat ? ff_w1 : in_proj) + l * 25600;
  fp g = (mat ? ln2_g : ln1_g) + l * 80;
  fp b = (mat ? ln2_b : ln1_b) + l * 80;
  float* wpo = wp + lm * 25600;
  float u = 0.f, v = 0.f;
  for (int k = 0; k < 80; ++k) {
    float w = W[k * 320 + c];
    float gw = g[k] * w;
    wpo[k * 320 + c] = gw;
    u += gw;
    v += b[k] * w;
  }
  if (mat) v += ff_b1[l * 320 + c];
  uvb[lm * 640 + c] = u;
  uvb[lm * 640 + 320 + c] = v;
}

// ---- prep: padded-164 weight copies for gof/gfi (needs wp -> after prepw) ---
__global__ __launch_bounds__(256) void prepg_k(fp out_proj, fp ff_w2,
    const float* __restrict__ wp, float* __restrict__ wotp,
    float* __restrict__ w1pp, float* __restrict__ w2tp, float* __restrict__ wpnp) {
  int idx = blockIdx.x * 256 + threadIdx.x;
  if (idx >= 1102080) return;
  int l = idx / 91840, r = idx % 91840;
  if (r < 13120) {
    int c = r / 164, k = r % 164;
    wotp[l * 13120 + r] = (k < 160) ? out_proj[l * 12800 + k * 80 + c] : 0.f;
  } else if (r < 39360) {
    int r2 = r - 13120; int h = r2 / 13120, r3 = r2 % 13120;
    int kr = r3 / 164, cq = r3 % 164;
    w1pp[l * 26240 + r2] = (cq < 160) ? wp[(2 * l + 1) * 25600 + kr * 320 + h * 160 + cq] : 0.f;
  } else if (r < 65600) {
    int r2 = r - 39360; int h = r2 / 13120, r3 = r2 % 13120;
    int c = r3 / 164, k = r3 % 164;
    w2tp[l * 26240 + r2] = (k < 160) ? ff_w2[l * 25600 + (h * 160 + k) * 80 + c] : 0.f;
  } else {
    int r2 = r - 65600; int h = r2 / 13120, r3 = r2 % 13120;
    int kr = r3 / 164, cq = r3 % 164;
    float v = 0.f;
    if (l < 11 && cq < 160) v = wp[(2 * l + 2) * 25600 + kr * 320 + h * 160 + cq];
    wpnp[l * 26240 + r2] = v;
  }
}

// ---- prep: transpose+pad x_proj -> xptp[l][37][164] -------------------------
__global__ __launch_bounds__(256) void prepx_k(fp x_proj, float* __restrict__ xptp) {
  int idx = blockIdx.x * 256 + threadIdx.x;   // 12*6068 = 72816
  if (idx >= 72816) return;
  int l = idx / 6068, r = idx % 6068;
  int c = r / 164, k = r % 164;
  xptp[idx] = (k < 160) ? x_proj[l * 5920 + k * 37 + c] : 0.f;
}

// ---- CMN + transpose: feat [B,C,T] -> x [B*T, C] ----------------------------
__global__ __launch_bounds__(256) void cmn_k(fp feat, float* __restrict__ x) {
  int bc = blockIdx.x;
  int b = bc / C_, c = bc % C_;
  const float* f = feat + (b * C_ + c) * T_;
  __shared__ float sb[4];
  int tid = threadIdx.x;
  float v[4]; float s = 0.f;
  #pragma unroll
  for (int i = 0; i < 4; ++i) {
    int t = tid + i * 256;
    v[i] = (t < T_) ? f[t] : 0.f;
    s += v[i];
  }
  s = blockSum(s, sb);
  float mu = s * (1.f / T_);
  #pragma unroll
  for (int i = 0; i < 4; ++i) {
    int t = tid + i * 256;
    if (t < T_) x[(b * T_ + t) * C_ + c] = v[i] - mu;
  }
}

// ---- row stats (mu, rs) for LN fold (layer-0 entry only) --------------------
__global__ __launch_bounds__(256) void rstat_k(const float* __restrict__ in,
                                               float* __restrict__ must) {
  int row = blockIdx.x * 16 + (threadIdx.x >> 4);
  int c16 = threadIdx.x & 15;
  float s = 0.f, q = 0.f;
  #pragma unroll
  for (int m = 0; m < 5; ++m) {
    float v = in[row * 80 + c16 + 16 * m];
    s += v; q += v * v;
  }
  s += __shfl_xor(s, 1); s += __shfl_xor(s, 2);
  s += __shfl_xor(s, 4); s += __shfl_xor(s, 8);
  q += __shfl_xor(q, 1); q += __shfl_xor(q, 2);
  q += __shfl_xor(q, 4); q += __shfl_xor(q, 8);
  if (c16 == 0) {
    float mu = s * 0.0125f;
    float rs = rsqrtf(fmaxf(q * 0.0125f - mu * mu, 0.f) + 1e-5f);
    must[row * 2] = mu;
    must[row * 2 + 1] = rs;
  }
}

// ---- per-wave GEMM, K=80, TN=64; EPI 0: LN-fold (entry), 3: att1 ------------
template<int EPI>
__global__ __launch_bounds__(256, 4) void gw_k(const float* __restrict__ A,
    fp W, fp uv, const float* __restrict__ must, const float* __restrict__ extra,
    float* __restrict__ out, int N) {
  __shared__ float SL[5120 + 4 * 1280];
  int tid = threadIdx.x, wv = tid >> 6, ln = tid & 63;
  int bid = blockIdx.x;
  int c0 = (bid / 50) * 64;
  int row0 = ((bid % 50) * 4 + wv) * 16;
  for (int ch = wv; ch < 20; ch += 4) {
    int m = ch * 256 + ln * 4;
    int kr = m >> 6, cc = m & 63;
    int lo = __builtin_amdgcn_readfirstlane(ch * 256);
    g2l16(W + kr * N + c0 + cc, SL + lo);
  }
  int abase = __builtin_amdgcn_readfirstlane(5120 + wv * 1280);
  float* As = SL + 5120 + wv * 1280;
  #pragma unroll
  for (int i = 0; i < 5; ++i) {
    int m = i * 256 + ln * 4;
    int r = m / 80, kk = m - r * 80;
    g2l16(A + (row0 + r) * 80 + kk, SL + abase + i * 256);
  }
  __syncthreads();
  int rq = ln >> 4, c16 = ln & 15;
  float acc[4][4] = {};
  #pragma unroll 2
  for (int k4 = 0; k4 < 80; k4 += 4) {
    float4 a[4], w[4];
    #pragma unroll
    for (int i = 0; i < 4; ++i)
      a[i] = *(const float4*)&As[(rq * 4 + i) * 80 + k4];
    #pragma unroll
    for (int kk = 0; kk < 4; ++kk)
      w[kk] = *(const float4*)&SL[(k4 + kk) * 64 + c16 * 4];
    #pragma unroll
    for (int i = 0; i < 4; ++i) {
      acc[i][0] += a[i].x*w[0].x + a[i].y*w[1].x + a[i].z*w[2].x + a[i].w*w[3].x;
      acc[i][1] += a[i].x*w[0].y + a[i].y*w[1].y + a[i].z*w[2].y + a[i].w*w[3].y;
      acc[i][2] += a[i].x*w[0].z + a[i].y*w[1].z + a[i].z*w[2].z + a[i].w*w[3].z;
      acc[i][3] += a[i].x*w[0].w + a[i].y*w[1].w + a[i].z*w[2].w + a[i].w*w[3].w;
    }
  }
  float ua[4], va[4];
  if (EPI != 3) {
    *(float4*)ua = *(const float4*)&uv[c0 + c16 * 4];
    *(float4*)va = *(const float4*)&uv[N + c0 + c16 * 4];
  }
  #pragma unroll
  for (int i = 0; i < 4; ++i) {
    int row = row0 + rq * 4 + i;
    float mu = 0.f, rs = 1.f;
    if (EPI != 3) {
      float2 ms = *(const float2*)&must[row * 2];
      mu = ms.x; rs = ms.y;
    }
    float4 o;
    float* op = &o.x;
    #pragma unroll
    for (int j = 0; j < 4; ++j) {
      float v = acc[i][j];
      if (EPI == 3) {
        int c = c0 + c16 * 4 + j;
        v += extra[(row / T_) * 128 + c];
        v = fmaxf(v, 0.f);
        v = v * extra[512 + c] + extra[640 + c];
        v = tanhf(v);
      } else {
        v = rs * v - mu * rs * ua[j] + va[j];
      }
      op[j] = v;
    }
    *(float4*)&out[row * N + c0 + c16 * 4] = o;
  }
}

// ---- block-coop GEMM (pooling att2 only) ------------------------------------
template<int EPI, int KCH, int NKC>
__global__ __launch_bounds__(256, 4) void gc_k(const float* __restrict__ A,
    fp W, fp bias, float* __restrict__ out, int Astride) {
  constexpr int P = KCH + 4;
  __shared__ float As[16 * P];
  __shared__ float Wt[80 * P];
  int tid = threadIdx.x;
  int row0 = blockIdx.x * 16;
  int rr = tid >> 4, c16 = tid & 15;
  float acc[5] = {};
  for (int kc = 0; kc < NKC; ++kc) {
    if (kc) __syncthreads();
    #pragma unroll
    for (int i = 0; i < 16 * KCH / 256; ++i) {
      int e = tid + i * 256;
      int r = e / KCH, k = e - r * KCH;
      As[r * P + k] = A[(row0 + r) * Astride + kc * KCH + k];
    }
    #pragma unroll
    for (int i = 0; i < KCH * 80 / 256; ++i) {
      int e = tid + i * 256;
      int kr = e / 80, c = e - kr * 80;
      Wt[c * P + kr] = W[(kc * KCH + kr) * 80 + c];
    }
    __syncthreads();
    #pragma unroll 4
    for (int k4 = 0; k4 < KCH; k4 += 4) {
      float4 a = *(const float4*)&As[rr * P + k4];
      #pragma unroll
      for (int m = 0; m < 5; ++m) {
        float4 w = *(const float4*)&Wt[(c16 + 16 * m) * P + k4];
        acc[m] += a.x * w.x + a.y * w.y + a.z * w.z + a.w * w.w;
      }
    }
  }
  int row = row0 + rr;
  #pragma unroll
  for (int m = 0; m < 5; ++m) {
    int c = c16 + 16 * m;
    float v = acc[m];
    if (EPI == 4) v += bias[c];
    out[row * 80 + c] = v;
  }
}

// ---- cxf: conv+SiLU + x_proj + dt+softplus; xpT async-staged ----------------
__global__ __launch_bounds__(256) void cxf_k(const float* __restrict__ xz,
    fp cw, fp cb, fp xptl, fp dtw, fp dtb,
    float* __restrict__ xcf, float* __restrict__ xcbb,
    float* __restrict__ dbc2, float* __restrict__ dt2) {
  __shared__ float As[16 * 164];
  __shared__ float xpT[37 * 164];
  __shared__ float dbcl[16 * 40];
  int bi = blockIdx.x;
  int tc = bi % 50; int rem = bi / 50;
  int b = rem & 3, dir = rem >> 2;
  int t0 = tc * 16;
  int tid = threadIdx.x;
  stageN<1517>(xpT, xptl, tid);   // 6068 floats, async
  float* xco = dir ? xcbb : xcf;
  #pragma unroll
  for (int i = 0; i < 3; ++i) {
    int e = tid + i * 256;
    if (e < 640) {
      int ii = e / 40, d4 = (e - ii * 40) * 4;
      int t = t0 + ii;
      float4 acc = *(const float4*)&cb[d4];
      #pragma unroll
      for (int k = 0; k < 4; ++k) {
        int tt = t - 3 + k;
        if (tt >= 0) {
          int src = dir ? (T_ - 1 - tt) : tt;
          float4 xv = *(const float4*)&xz[(b * T_ + src) * 320 + d4];
          float4 wv = *(const float4*)&cw[k * DIN + d4];
          acc.x += wv.x * xv.x; acc.y += wv.y * xv.y;
          acc.z += wv.z * xv.z; acc.w += wv.w * xv.w;
        }
      }
      float4 o;
      o.x = acc.x / (1.f + __expf(-acc.x));
      o.y = acc.y / (1.f + __expf(-acc.y));
      o.z = acc.z / (1.f + __expf(-acc.z));
      o.w = acc.w / (1.f + __expf(-acc.w));
      *(float4*)&As[ii * 164 + d4] = o;
      *(float4*)&xco[(b * T_ + t) * DIN + d4] = o;
    }
  }
  __syncthreads();
  int rr = tid >> 4, c16 = tid & 15;
  int grow0 = dir * R_ + b * T_ + t0;
  {
    float a0 = 0.f, a1 = 0.f, a2 = 0.f;
    for (int k4 = 0; k4 < 160; k4 += 4) {
      float4 a = *(const float4*)&As[rr * 164 + k4];
      float4 w0 = *(const float4*)&xpT[c16 * 164 + k4];
      float4 w1 = *(const float4*)&xpT[(c16 + 16) * 164 + k4];
      a0 += a.x * w0.x + a.y * w0.y + a.z * w0.z + a.w * w0.w;
      a1 += a.x * w1.x + a.y * w1.y + a.z * w1.z + a.w * w1.w;
      if (c16 < 5) {
        float4 w2 = *(const float4*)&xpT[(c16 + 32) * 164 + k4];
        a2 += a.x * w2.x + a.y * w2.y + a.z * w2.z + a.w * w2.w;
      }
    }
    dbcl[rr * 40 + c16] = a0;
    dbcl[rr * 40 + c16 + 16] = a1;
    dbc2[(grow0 + rr) * 37 + c16] = a0;
    dbc2[(grow0 + rr) * 37 + c16 + 16] = a1;
    if (c16 < 5) {
      dbcl[rr * 40 + c16 + 32] = a2;
      dbc2[(grow0 + rr) * 37 + c16 + 32] = a2;
    }
  }
  __syncthreads();
  #pragma unroll
  for (int i = 0; i < 10; ++i) {
    int e = tid + i * 256;
    int ii = e / 160, d = e - ii * 160;
    float v = dtb[d];
    #pragma unroll
    for (int m = 0; m < 5; ++m) v += dbcl[ii * 40 + m] * dtw[m * DIN + d];
    v = fmaxf(v, 0.f) + __logf(1.f + __expf(-fabsf(v)));
    dt2[(grow0 + ii) * DIN + d] = v;
  }
}

// ---- scanA: per-chunk (prod, h_end) with h0=0; async 4B staging -------------
__global__ __launch_bounds__(256) void scanA_k(const float* __restrict__ dt2,
    const float* __restrict__ xcf, const float* __restrict__ xcbb,
    const float* __restrict__ dbc2, fp A_log,
    float* __restrict__ hend, float* __restrict__ pprod) {
  __shared__ float sdt[800], sX[800], sB[800];
  int bi = blockIdx.x;
  int cch = bi % NC; int rem = bi / NC;
  int dblk = rem % 10; rem /= 10;
  int b = rem % 4; int dir = rem / 4;
  int d0 = dblk * 16;
  int tid = threadIdx.x, dl = tid >> 4, n = tid & 15;
  int d = d0 + dl;
  const float* xc = dir ? xcbb : xcf;
  int rbase = dir * R_ + b * T_ + cch * LCH;
  int rloc0 = b * T_ + cch * LCH;
  int wv = tid >> 6, ln = tid & 63;
  #pragma unroll
  for (int i = 0; i < 4; ++i) {
    int cbase = i * 256 + wv * 64;
    int e = cbase + ln;
    if (e < 800) {
      int ii = e >> 4, jj = e & 15;
      int lo = __builtin_amdgcn_readfirstlane(cbase);
      g2l4(dt2 + (rbase + ii) * DIN + d0 + jj, sdt + lo);
      g2l4(xc + (rloc0 + ii) * DIN + d0 + jj, sX + lo);
      g2l4(dbc2 + (rbase + ii) * 37 + 5 + jj, sB + lo);
    }
  }
  float Areg = -__expf(A_log[d * NST + n]);
  __syncthreads();
  float h = 0.f, dts = 0.f;
  #pragma unroll 2
  for (int i = 0; i < LCH; ++i) {
    float dtv = sdt[i * 16 + dl];
    float aa = __expf(dtv * Areg);
    h = aa * h + dtv * sX[i * 16 + dl] * sB[i * 16 + n];
    dts += dtv;
  }
  hend[bi * 256 + tid] = h;
  pprod[bi * 256 + tid] = __expf(dts * Areg);
}

// ---- scanC: fused prefix + recompute + gated write; async 4B staging --------
__global__ __launch_bounds__(256) void scanC_k(const float* __restrict__ dt2,
    const float* __restrict__ dbc2, const float* __restrict__ xcf,
    const float* __restrict__ xcbb, const float* __restrict__ xz,
    fp A_log, fp Dp, const float* __restrict__ hend,
    const float* __restrict__ pprod, float* __restrict__ ygcat) {
  __shared__ float sdt[800], sX[800], sB[800], sC[800], sY[800];
  int bi = blockIdx.x;
  int cch = bi % NC; int rem = bi / NC;
  int dblk = rem % 10; rem /= 10;
  int b = rem % 4; int dir = rem / 4;
  int d0 = dblk * 16;
  int tid = threadIdx.x, dl = tid >> 4, n = tid & 15;
  int d = d0 + dl;
  const float* xc = dir ? xcbb : xcf;
  int rbase = dir * R_ + b * T_ + cch * LCH;
  int rloc0 = b * T_ + cch * LCH;
  int wv = tid >> 6, ln = tid & 63;
  #pragma unroll
  for (int i = 0; i < 4; ++i) {
    int cbase = i * 256 + wv * 64;
    int e = cbase + ln;
    if (e < 800) {
      int ii = e >> 4, jj = e & 15;
      int lo = __builtin_amdgcn_readfirstlane(cbase);
      g2l4(dt2 + (rbase + ii) * DIN + d0 + jj, sdt + lo);
      g2l4(xc + (rloc0 + ii) * DIN + d0 + jj, sX + lo);
      g2l4(dbc2 + (rbase + ii) * 37 + 5 + jj, sB + lo);
      g2l4(dbc2 + (rbase + ii) * 37 + 21 + jj, sC + lo);
    }
  }
  float Areg = -__expf(A_log[d * NST + n]);
  // fused prefix over earlier chunk summaries
  int sbase = (bi / NC) * (NC * 256) + tid;
  float h = 0.f;
  #pragma unroll
  for (int cc = 0; cc < NC; ++cc) {
    float p = pprod[sbase + cc * 256];
    float e = hend[sbase + cc * 256];
    if (cc < cch) h = p * h + e;
  }
  __syncthreads();
  for (int i = 0; i < LCH; ++i) {
    float dtv = sdt[i * 16 + dl];
    float a = __expf(dtv * Areg);
    h = a * h + dtv * sX[i * 16 + dl] * sB[i * 16 + n];
    float y = h * sC[i * 16 + n];
    y += __shfl_xor(y, 1);
    y += __shfl_xor(y, 2);
    y += __shfl_xor(y, 4);
    y += __shfl_xor(y, 8);
    if (n == 0) sY[i * 16 + dl] = y;
  }
  __syncthreads();
  for (int e = tid; e < LCH * 16; e += 256) {
    int i = e >> 4, jj = e & 15;
    int t = cch * LCH + i;
    float xcv = sX[i * 16 + jj];
    int orow = dir ? (b * T_ + (T_ - 1 - t)) : (b * T_ + t);
    float z = xz[orow * 320 + 160 + d0 + jj];
    float sg = 1.f / (1.f + __expf(-z));
    ygcat[orow * 320 + dir * 160 + d0 + jj] = (sY[i * 16 + jj] + xcv * Dp[d0 + jj]) * (z * sg);
  }
}

// ---- gof: out_proj(sum fwd/bwd) + in-block LN2 + ff1 + GELU -----------------
__global__ __launch_bounds__(256, 2) void gof_k(const float* __restrict__ yg,
    fp wotp_l, fp w1pp_l, fp uv1, float* __restrict__ g1) {
  __shared__ float S[17120];
  float* Wt = S;             // [80][164]
  float* As = S + 13120;     // [16][164]
  float* sl = S + 15744;     // [16][84]
  float* ss = S + 17088;     // [32]
  int tid = threadIdx.x, row0 = blockIdx.x * 16, rr = tid >> 4, c16 = tid & 15;
  stageN<3280>(Wt, wotp_l, tid);
  #pragma unroll
  for (int i = 0; i < 10; ++i) {
    int e = tid + i * 256; int r = e / 160, k = e - r * 160;
    As[r * 164 + k] = yg[(row0 + r) * 320 + k] + yg[(row0 + r) * 320 + 160 + k];
  }
  __syncthreads();
  {
    float acc[5] = {};
    #pragma unroll 4
    for (int k4 = 0; k4 < 160; k4 += 4) {
      float4 a = *(const float4*)&As[rr * 164 + k4];
      #pragma unroll
      for (int m = 0; m < 5; ++m) {
        float4 w = *(const float4*)&Wt[(c16 + 16 * m) * 164 + k4];
        acc[m] += a.x * w.x + a.y * w.y + a.z * w.z + a.w * w.w;
      }
    }
    float s = 0.f, q = 0.f;
    #pragma unroll
    for (int m = 0; m < 5; ++m) {
      float v = acc[m];
      sl[rr * 84 + c16 + 16 * m] = v;
      s += v; q += v * v;
    }
    s += __shfl_xor(s, 1); s += __shfl_xor(s, 2);
    s += __shfl_xor(s, 4); s += __shfl_xor(s, 8);
    q += __shfl_xor(q, 1); q += __shfl_xor(q, 2);
    q += __shfl_xor(q, 4); q += __shfl_xor(q, 8);
    if (c16 == 0) {
      float mu = s * 0.0125f;
      ss[rr * 2] = mu;
      ss[rr * 2 + 1] = rsqrtf(fmaxf(q * 0.0125f - mu * mu, 0.f) + 1e-5f);
    }
  }
  for (int h = 0; h < 2; ++h) {
    __syncthreads();
    stageN<3280>(Wt, w1pp_l + h * 13120, tid);
    __syncthreads();
    float mu = ss[rr * 2], rs = ss[rr * 2 + 1];
    float a2[10] = {};
    for (int k = 0; k < 80; k += 4) {
      float4 av = *(const float4*)&sl[rr * 84 + k];
      #pragma unroll
      for (int m = 0; m < 10; ++m) {
        int c = c16 + 16 * m;
        a2[m] += av.x * Wt[k * 164 + c] + av.y * Wt[(k + 1) * 164 + c]
               + av.z * Wt[(k + 2) * 164 + c] + av.w * Wt[(k + 3) * 164 + c];
      }
    }
    #pragma unroll
    for (int m = 0; m < 10; ++m) {
      int c = h * 160 + c16 + 16 * m;
      float v = rs * a2[m] - mu * rs * uv1[c] + uv1[320 + c];
      v = 0.5f * v * (1.f + erff(v * 0.70710678118f));
      g1[(row0 + rr) * 320 + c] = v;
    }
  }
}

// ---- gfi: ff2 + bias + residual + in-block LN1 + next in_proj ---------------
template<int LAST>
__global__ __launch_bounds__(256, 2) void gfi_k(const float* __restrict__ g1,
    fp w2tp_l, fp fb2, float* __restrict__ x, fp wpnp_l, fp uvn,
    float* __restrict__ xz) {
  __shared__ float S[17120];
  float* Wt = S;             // [80][164]
  float* As = S + 13120;     // [16][164]
  float* xn = S + 15744;     // [16][84]
  float* ss = S + 17088;     // [32]
  int tid = threadIdx.x, row0 = blockIdx.x * 16, rr = tid >> 4, c16 = tid & 15;
  float acc2[5] = {};
  for (int kc = 0; kc < 2; ++kc) {
    if (kc) __syncthreads();
    stageN<3280>(Wt, w2tp_l + kc * 13120, tid);
    #pragma unroll
    for (int i = 0; i < 10; ++i) {
      int e = tid + i * 256; int r = e / 160, k = e - r * 160;
      As[r * 164 + k] = g1[(row0 + r) * 320 + kc * 160 + k];
    }
    __syncthreads();
    #pragma unroll 4
    for (int k4 = 0; k4 < 160; k4 += 4) {
      float4 a = *(const float4*)&As[rr * 164 + k4];
      #pragma unroll
      for (int m = 0; m < 5; ++m) {
        float4 w = *(const float4*)&Wt[(c16 + 16 * m) * 164 + k4];
        acc2[m] += a.x * w.x + a.y * w.y + a.z * w.z + a.w * w.w;
      }
    }
  }
  {
    float s = 0.f, q = 0.f;
    #pragma unroll
    for (int m = 0; m < 5; ++m) {
      int c = c16 + 16 * m;
      float v = acc2[m] + fb2[c] + x[(row0 + rr) * 80 + c];
      x[(row0 + rr) * 80 + c] = v;
      xn[rr * 84 + c] = v;
      s += v; q += v * v;
    }
    if (!LAST) {
      s += __shfl_xor(s, 1); s += __shfl_xor(s, 2);
      s += __shfl_xor(s, 4); s += __shfl_xor(s, 8);
      q += __shfl_xor(q, 1); q += __shfl_xor(q, 2);
      q += __shfl_xor(q, 4); q += __shfl_xor(q, 8);
      if (c16 == 0) {
        float mu = s * 0.0125f;
        ss[rr * 2] = mu;
        ss[rr * 2 + 1] = rsqrtf(fmaxf(q * 0.0125f - mu * mu, 0.f) + 1e-5f);
      }
    }
  }
  if (!LAST) {
    for (int h = 0; h < 2; ++h) {
      __syncthreads();
      stageN<3280>(Wt, wpnp_l + h * 13120, tid);
      __syncthreads();
      float mu = ss[rr * 2], rs = ss[rr * 2 + 1];
      float a3[10] = {};
      for (int k = 0; k < 80; k += 4) {
        float4 av = *(const float4*)&xn[rr * 84 + k];
        #pragma unroll
        for (int m = 0; m < 10; ++m) {
          int c = c16 + 16 * m;
          a3[m] += av.x * Wt[k * 164 + c] + av.y * Wt[(k + 1) * 164 + c]
                 + av.z * Wt[(k + 2) * 164 + c] + av.w * Wt[(k + 3) * 164 + c];
        }
      }
      #pragma unroll
      for (int m = 0; m < 10; ++m) {
        int c = h * 160 + c16 + 16 * m;
        xz[(row0 + rr) * 320 + c] = rs * a3[m] - mu * rs * uvn[c] + uvn[320 + c];
      }
    }
  }
}

// ---- pooling: per-(b,c) mean/std over T -------------------------------------
__global__ __launch_bounds__(256) void stats_k(const float* __restrict__ x,
                                               float* __restrict__ meanv, float* __restrict__ stdv) {
  int bc = blockIdx.x; int b = bc / C_, c = bc % C_;
  __shared__ float sb[4];
  int tid = threadIdx.x;
  float v[4]; float s = 0.f;
  #pragma unroll
  for (int i = 0; i < 4; ++i) {
    int t = tid + i * 256;
    v[i] = (t < T_) ? x[(b * T_ + t) * C_ + c] : 0.f;
    s += v[i];
  }
  s = blockSum(s, sb);
  float mu = s * (1.f / T_);
  float q = 0.f;
  #pragma unroll
  for (int i = 0; i < 4; ++i) {
    int t = tid + i * 256;
    if (t < T_) { float dd = v[i] - mu; q += dd * dd; }
  }
  q = blockSum(q, sb);
  if (tid == 0) { meanv[bc] = mu; stdv[bc] = sqrtf(fmaxf(q * (1.f / T_), 1e-12f)); }
}

// ---- att1 pack --------------------------------------------------------------
__global__ __launch_bounds__(256) void prep_k(const float* __restrict__ meanv,
    const float* __restrict__ stdv, fp w1, fp ab1, fp g1p, fp b1p, fp m1p, fp v1p,
    float* __restrict__ pack) {
  int idx = blockIdx.x * 256 + threadIdx.x;
  if (idx < 512) {
    int b = idx / 128, dcol = idx % 128;
    float acc = ab1[dcol];
    for (int c = 0; c < C_; ++c) {
      acc += meanv[b * C_ + c] * w1[(C_ + c) * 128 + dcol];
      acc += stdv[b * C_ + c] * w1[(2 * C_ + c) * 128 + dcol];
    }
    pack[idx] = acc;
  } else if (idx < 640) {
    int dcol = idx - 512;
    float kv = g1p[dcol] * rsqrtf(v1p[dcol] + 1e-5f);
    pack[512 + dcol] = kv;
    pack[640 + dcol] = b1p[dcol] - m1p[dcol] * kv;
  }
}

// ---- softmax over T + weighted stats + bn2 ----------------------------------
__global__ __launch_bounds__(256) void pool_k(const float* __restrict__ x,
    const float* __restrict__ scores, fp g2, fp b2, fp m2, fp v2,
    float* __restrict__ pooledn) {
  int bc = blockIdx.x; int b = bc / C_, c = bc % C_;
  __shared__ float sb[4];
  int tid = threadIdx.x;
  float sv[4], xv[4];
  float mx = -1e30f;
  #pragma unroll
  for (int i = 0; i < 4; ++i) {
    int t = tid + i * 256;
    if (t < T_) { sv[i] = scores[(b * T_ + t) * C_ + c]; xv[i] = x[(b * T_ + t) * C_ + c]; }
    else { sv[i] = -1e30f; xv[i] = 0.f; }
    mx = fmaxf(mx, sv[i]);
  }
  mx = blockMax(mx, sb);
  float se = 0.f, sx = 0.f, sxx = 0.f;
  #pragma unroll
  for (int i = 0; i < 4; ++i) {
    float e = expf(sv[i] - mx);
    se += e; sx += e * xv[i]; sxx += e * xv[i] * xv[i];
  }
  se = blockSum(se, sb);
  sx = blockSum(sx, sb);
  sxx = blockSum(sxx, sb);
  if (tid == 0) {
    float mu = sx / se;
    float sg = sqrtf(fmaxf(sxx / se - mu * mu, 1e-12f));
    int j0 = c, j1 = C_ + c;
    pooledn[b * 160 + j0] = (mu - m2[j0]) * rsqrtf(v2[j0] + 1e-5f) * g2[j0] + b2[j0];
    pooledn[b * 160 + j1] = (sg - m2[j1]) * rsqrtf(v2[j1] + 1e-5f) * g2[j1] + b2[j1];
  }
}

// ---- final fc ---------------------------------------------------------------
__global__ __launch_bounds__(256) void fc_k(const float* __restrict__ pooledn, fp fw, fp fb,
                                            float* __restrict__ out) {
  int idx = blockIdx.x * 256 + threadIdx.x;
  if (idx >= 4 * 192) return;
  int b = idx / 192, e = idx % 192;
  float acc = fb[e];
  for (int i = 0; i < 160; ++i) acc += pooledn[b * 160 + i] * fw[i * 192 + e];
  out[idx] = acc;
}

extern "C" void kernel_launch(void* const* d_in, const int* in_sizes, int n_in,
                              void* d_out, int out_size, void* d_ws, size_t ws_size,
                              hipStream_t stream) {
  fp feat   = (fp)d_in[0];
  fp ln1_g  = (fp)d_in[1];  fp ln1_b  = (fp)d_in[2];
  fp in_proj= (fp)d_in[3];
  fp conv_w = (fp)d_in[4];  fp conv_b = (fp)d_in[5];
  fp x_proj = (fp)d_in[6];
  fp dt_w   = (fp)d_in[7];  fp dt_b   = (fp)d_in[8];
  fp A_log  = (fp)d_in[9];  fp Dp     = (fp)d_in[10];
  fp out_proj=(fp)d_in[11];
  fp ln2_g  = (fp)d_in[12]; fp ln2_b  = (fp)d_in[13];
  fp ff_w1  = (fp)d_in[14]; fp ff_b1  = (fp)d_in[15];
  fp ff_w2  = (fp)d_in[16]; fp ff_b2  = (fp)d_in[17];
  fp att_w1 = (fp)d_in[18]; fp att_b1 = (fp)d_in[19];
  fp bn1_g  = (fp)d_in[20]; fp bn1_b  = (fp)d_in[21];
  fp bn1_m  = (fp)d_in[22]; fp bn1_v  = (fp)d_in[23];
  fp att_w2 = (fp)d_in[24]; fp att_b2 = (fp)d_in[25];
  fp bn2_g  = (fp)d_in[26]; fp bn2_b  = (fp)d_in[27];
  fp bn2_m  = (fp)d_in[28]; fp bn2_v  = (fp)d_in[29];
  fp fc_w   = (fp)d_in[30]; fp fc_b   = (fp)d_in[31];

  float* ws   = (float*)d_ws;
  float* x    = ws;               // 256000
  float* xz   = ws + 256000;      // 1024000
  float* xcf  = ws + 1280000;     // 512000
  float* xcb  = ws + 1792000;     // 512000
  float* dbc2 = ws + 2304000;     // 236800
  float* dt2  = ws + 2540800;     // 1024000
  float* hend = ws + 3564800;     // 327680
  float* pprod= ws + 3892480;     // 327680
  float* ygcat= ws + 4220160;     // 1024000
  float* meanv= ws + 5244160;     // 320
  float* stdv = ws + 5244480;     // 320
  float* pack = ws + 5244800;     // 768
  float* pooledn = ws + 5245568;  // 640
  float* wp   = ws + 5246208;     // 614400
  float* uvb  = ws + 5860608;     // 15360
  float* mst_x= ws + 5875968;     // 6400
  float* xptp = ws + 5882368;     // 72816
  float* wotp = ws + 5955184;     // 157440
  float* w1pp = ws + 6112624;     // 314880
  float* w2tp = ws + 6427504;     // 314880
  float* wpnp = ws + 6742384;     // 314880  (end 7057264 = 28.2 MiB)
  float* g1   = xz;               // alias: xz free after scanC
  float* a1b  = hend;             // alias: pooling only (hend+pprod region)
  float* sc   = dt2;              // alias: pooling only

  prepw_k<<<30, 256, 0, stream>>>(in_proj, ff_w1, ln1_g, ln1_b, ln2_g, ln2_b,
                                  ff_b1, wp, uvb);
  prepg_k<<<4305, 256, 0, stream>>>(out_proj, ff_w2, wp, wotp, w1pp, w2tp, wpnp);
  prepx_k<<<285, 256, 0, stream>>>(x_proj, xptp);
  cmn_k<<<320, 256, 0, stream>>>(feat, x);
  rstat_k<<<200, 256, 0, stream>>>(x, mst_x);
  gw_k<0><<<250, 256, 0, stream>>>(x, wp, uvb, mst_x, nullptr, xz, 320);

  for (int l = 0; l < 12; ++l) {
    cxf_k<<<400, 256, 0, stream>>>(xz, conv_w + l * 640, conv_b + l * 160,
                                   xptp + l * 6068, dt_w + l * 800, dt_b + l * 160,
                                   xcf, xcb, dbc2, dt2);
    scanA_k<<<1280, 256, 0, stream>>>(dt2, xcf, xcb, dbc2, A_log + l * 2560,
                                      hend, pprod);
    scanC_k<<<1280, 256, 0, stream>>>(dt2, dbc2, xcf, xcb, xz, A_log + l * 2560,
                                      Dp + l * 160, hend, pprod, ygcat);
    gof_k<<<200, 256, 0, stream>>>(ygcat, wotp + l * 13120, w1pp + l * 26240,
                                   uvb + (2 * l + 1) * 640, g1);
    if (l < 11)
      gfi_k<0><<<200, 256, 0, stream>>>(g1, w2tp + l * 26240, ff_b2 + l * 80, x,
                                        wpnp + l * 26240, uvb + (2 * l + 2) * 640, xz);
    else
      gfi_k<1><<<200, 256, 0, stream>>>(g1, w2tp + l * 26240, ff_b2 + l * 80, x,
                                        wpnp + l * 26240, uvb, xz);
  }

  stats_k<<<320, 256, 0, stream>>>(x, meanv, stdv);
  prep_k<<<3, 256, 0, stream>>>(meanv, stdv, att_w1, att_b1, bn1_g, bn1_b, bn1_m, bn1_v, pack);
  gw_k<3><<<100, 256, 0, stream>>>(x, att_w1, nullptr, nullptr, pack, a1b, 128);
  gc_k<4, 128, 1><<<200, 256, 0, stream>>>(a1b, att_w2, att_b2, sc, 128);
  pool_k<<<320, 256, 0, stream>>>(x, sc, bn2_g, bn2_b, bn2_m, bn2_v, pooledn);
  fc_k<<<3, 256, 0, stream>>>(pooledn, fc_w, fc_b, (float*)d_out);
}

// Round 15
// 1139.739 us; speedup vs baseline: 4.3987x; 1.0279x over previous
//
#include <hip/hip_runtime.h>
#include <hip/hip_bf16.h>

#define B_ 4
#define C_ 80
#define T_ 800
#define R_ 3200   // B_*T_
#define DIN 160
#define NST 16
#define NC 16     // time chunks for parallel scan
#define LCH 50    // T_/NC

typedef const float* fp;

__device__ __forceinline__ void g2l16(const float* g, float* l) {
  __builtin_amdgcn_global_load_lds(
      (const __attribute__((address_space(1))) void*)g,
      (__attribute__((address_space(3))) void*)l,
      16, 0, 0);
}
__device__ __forceinline__ void g2l4(const float* g, float* l) {
  __builtin_amdgcn_global_load_lds(
      (const __attribute__((address_space(1))) void*)g,
      (__attribute__((address_space(3))) void*)l,
      4, 0, 0);
}

// async linear stage of NF4 float4s into LDS (dest lane-linear per wave)
template<int NF4>
__device__ __forceinline__ void stageN(float* dst, const float* src, int tid) {
  int wv = tid >> 6, ln = tid & 63;
  constexpr int NP = (NF4 + 255) / 256;
  #pragma unroll
  for (int i = 0; i < NP; ++i) {
    int cbase = i * 256 + wv * 64;
    if (cbase + ln < NF4) {
      int lo = __builtin_amdgcn_readfirstlane(cbase * 4);
      g2l16(src + (cbase + ln) * 4, dst + lo);
    }
  }
}

__device__ __forceinline__ float blockSum(float v, float* sb) {
  for (int o = 32; o; o >>= 1) v += __shfl_xor(v, o);
  __syncthreads();
  if ((threadIdx.x & 63) == 0) sb[threadIdx.x >> 6] = v;
  __syncthreads();
  return sb[0] + sb[1] + sb[2] + sb[3];
}
__device__ __forceinline__ float blockMax(float v, float* sb) {
  for (int o = 32; o; o >>= 1) v = fmaxf(v, __shfl_xor(v, o));
  __syncthreads();
  if ((threadIdx.x & 63) == 0) sb[threadIdx.x >> 6] = v;
  __syncthreads();
  return fmaxf(fmaxf(sb[0], sb[1]), fmaxf(sb[2], sb[3]));
}

// ---- prep: W' = diag(g)W, u = colsum(W'), v = b@W (+bias), all 12 layers ----
__global__ __launch_bounds__(256) void prepw_k(fp in_proj, fp ff_w1,
    fp ln1_g, fp ln1_b, fp ln2_g, fp ln2_b, fp ff_b1,
    float* __restrict__ wp, float* __restrict__ uvb) {
  int idx = blockIdx.x * 256 + threadIdx.x;   // 0..7679
  int c = idx % 320, lm = idx / 320;
  int mat = lm & 1, l = lm >> 1;
  fp W = (mat ? ff_w1 : in_proj) + l * 25600;
  fp g = (mat ? ln2_g : ln1_g) + l * 80;
  fp b = (mat ? ln2_b : ln1_b) + l * 80;
  float* wpo = wp + lm * 25600;
  float u = 0.f, v = 0.f;
  for (int k = 0; k < 80; ++k) {
    float w = W[k * 320 + c];
    float gw = g[k] * w;
    wpo[k * 320 + c] = gw;
    u += gw;
    v += b[k] * w;
  }
  if (mat) v += ff_b1[l * 320 + c];
  uvb[lm * 640 + c] = u;
  uvb[lm * 640 + 320 + c] = v;
}

// ---- prep: padded-164 weight copies for gof/gfi (needs wp -> after prepw) ---
__global__ __launch_bounds__(256) void prepg_k(fp out_proj, fp ff_w2,
    const float* __restrict__ wp, float* __restrict__ wotp,
    float* __restrict__ w1pp, float* __restrict__ w2tp, float* __restrict__ wpnp) {
  int idx = blockIdx.x * 256 + threadIdx.x;
  if (idx >= 1102080) return;
  int l = idx / 91840, r = idx % 91840;
  if (r < 13120) {
    int c = r / 164, k = r % 164;
    wotp[l * 13120 + r] = (k < 160) ? out_proj[l * 12800 + k * 80 + c] : 0.f;
  } else if (r < 39360) {
    int r2 = r - 13120; int h = r2 / 13120, r3 = r2 % 13120;
    int kr = r3 / 164, cq = r3 % 164;
    w1pp[l * 26240 + r2] = (cq < 160) ? wp[(2 * l + 1) * 25600 + kr * 320 + h * 160 + cq] : 0.f;
  } else if (r < 65600) {
    int r2 = r - 39360; int h = r2 / 13120, r3 = r2 % 13120;
    int c = r3 / 164, k = r3 % 164;
    w2tp[l * 26240 + r2] = (k < 160) ? ff_w2[l * 25600 + (h * 160 + k) * 80 + c] : 0.f;
  } else {
    int r2 = r - 65600; int h = r2 / 13120, r3 = r2 % 13120;
    int kr = r3 / 164, cq = r3 % 164;
    float v = 0.f;
    if (l < 11 && cq < 160) v = wp[(2 * l + 2) * 25600 + kr * 320 + h * 160 + cq];
    wpnp[l * 26240 + r2] = v;
  }
}

// ---- prep: transpose+pad x_proj -> xptp[l][37][164] -------------------------
__global__ __launch_bounds__(256) void prepx_k(fp x_proj, float* __restrict__ xptp) {
  int idx = blockIdx.x * 256 + threadIdx.x;   // 12*6068 = 72816
  if (idx >= 72816) return;
  int l = idx / 6068, r = idx % 6068;
  int c = r / 164, k = r % 164;
  xptp[idx] = (k < 160) ? x_proj[l * 5920 + k * 37 + c] : 0.f;
}

// ---- CMN + transpose: feat [B,C,T] -> x [B*T, C] ----------------------------
__global__ __launch_bounds__(256) void cmn_k(fp feat, float* __restrict__ x) {
  int bc = blockIdx.x;
  int b = bc / C_, c = bc % C_;
  const float* f = feat + (b * C_ + c) * T_;
  __shared__ float sb[4];
  int tid = threadIdx.x;
  float v[4]; float s = 0.f;
  #pragma unroll
  for (int i = 0; i < 4; ++i) {
    int t = tid + i * 256;
    v[i] = (t < T_) ? f[t] : 0.f;
    s += v[i];
  }
  s = blockSum(s, sb);
  float mu = s * (1.f / T_);
  #pragma unroll
  for (int i = 0; i < 4; ++i) {
    int t = tid + i * 256;
    if (t < T_) x[(b * T_ + t) * C_ + c] = v[i] - mu;
  }
}

// ---- row stats (mu, rs) for LN fold (layer-0 entry only) --------------------
__global__ __launch_bounds__(256) void rstat_k(const float* __restrict__ in,
                                               float* __restrict__ must) {
  int row = blockIdx.x * 16 + (threadIdx.x >> 4);
  int c16 = threadIdx.x & 15;
  float s = 0.f, q = 0.f;
  #pragma unroll
  for (int m = 0; m < 5; ++m) {
    float v = in[row * 80 + c16 + 16 * m];
    s += v; q += v * v;
  }
  s += __shfl_xor(s, 1); s += __shfl_xor(s, 2);
  s += __shfl_xor(s, 4); s += __shfl_xor(s, 8);
  q += __shfl_xor(q, 1); q += __shfl_xor(q, 2);
  q += __shfl_xor(q, 4); q += __shfl_xor(q, 8);
  if (c16 == 0) {
    float mu = s * 0.0125f;
    float rs = rsqrtf(fmaxf(q * 0.0125f - mu * mu, 0.f) + 1e-5f);
    must[row * 2] = mu;
    must[row * 2 + 1] = rs;
  }
}

// ---- per-wave GEMM, K=80, TN=64; EPI 0: LN-fold (entry), 3: att1 ------------
template<int EPI>
__global__ __launch_bounds__(256, 4) void gw_k(const float* __restrict__ A,
    fp W, fp uv, const float* __restrict__ must, const float* __restrict__ extra,
    float* __restrict__ out, int N) {
  __shared__ float SL[5120 + 4 * 1280];
  int tid = threadIdx.x, wv = tid >> 6, ln = tid & 63;
  int bid = blockIdx.x;
  int c0 = (bid / 50) * 64;
  int row0 = ((bid % 50) * 4 + wv) * 16;
  for (int ch = wv; ch < 20; ch += 4) {
    int m = ch * 256 + ln * 4;
    int kr = m >> 6, cc = m & 63;
    int lo = __builtin_amdgcn_readfirstlane(ch * 256);
    g2l16(W + kr * N + c0 + cc, SL + lo);
  }
  int abase = __builtin_amdgcn_readfirstlane(5120 + wv * 1280);
  float* As = SL + 5120 + wv * 1280;
  #pragma unroll
  for (int i = 0; i < 5; ++i) {
    int m = i * 256 + ln * 4;
    int r = m / 80, kk = m - r * 80;
    g2l16(A + (row0 + r) * 80 + kk, SL + abase + i * 256);
  }
  __syncthreads();
  int rq = ln >> 4, c16 = ln & 15;
  float acc[4][4] = {};
  #pragma unroll 2
  for (int k4 = 0; k4 < 80; k4 += 4) {
    float4 a[4], w[4];
    #pragma unroll
    for (int i = 0; i < 4; ++i)
      a[i] = *(const float4*)&As[(rq * 4 + i) * 80 + k4];
    #pragma unroll
    for (int kk = 0; kk < 4; ++kk)
      w[kk] = *(const float4*)&SL[(k4 + kk) * 64 + c16 * 4];
    #pragma unroll
    for (int i = 0; i < 4; ++i) {
      acc[i][0] += a[i].x*w[0].x + a[i].y*w[1].x + a[i].z*w[2].x + a[i].w*w[3].x;
      acc[i][1] += a[i].x*w[0].y + a[i].y*w[1].y + a[i].z*w[2].y + a[i].w*w[3].y;
      acc[i][2] += a[i].x*w[0].z + a[i].y*w[1].z + a[i].z*w[2].z + a[i].w*w[3].z;
      acc[i][3] += a[i].x*w[0].w + a[i].y*w[1].w + a[i].z*w[2].w + a[i].w*w[3].w;
    }
  }
  float ua[4], va[4];
  if (EPI != 3) {
    *(float4*)ua = *(const float4*)&uv[c0 + c16 * 4];
    *(float4*)va = *(const float4*)&uv[N + c0 + c16 * 4];
  }
  #pragma unroll
  for (int i = 0; i < 4; ++i) {
    int row = row0 + rq * 4 + i;
    float mu = 0.f, rs = 1.f;
    if (EPI != 3) {
      float2 ms = *(const float2*)&must[row * 2];
      mu = ms.x; rs = ms.y;
    }
    float4 o;
    float* op = &o.x;
    #pragma unroll
    for (int j = 0; j < 4; ++j) {
      float v = acc[i][j];
      if (EPI == 3) {
        int c = c0 + c16 * 4 + j;
        v += extra[(row / T_) * 128 + c];
        v = fmaxf(v, 0.f);
        v = v * extra[512 + c] + extra[640 + c];
        v = tanhf(v);
      } else {
        v = rs * v - mu * rs * ua[j] + va[j];
      }
      op[j] = v;
    }
    *(float4*)&out[row * N + c0 + c16 * 4] = o;
  }
}

// ---- block-coop GEMM (pooling att2 only) ------------------------------------
template<int EPI, int KCH, int NKC>
__global__ __launch_bounds__(256, 4) void gc_k(const float* __restrict__ A,
    fp W, fp bias, float* __restrict__ out, int Astride) {
  constexpr int P = KCH + 4;
  __shared__ float As[16 * P];
  __shared__ float Wt[80 * P];
  int tid = threadIdx.x;
  int row0 = blockIdx.x * 16;
  int rr = tid >> 4, c16 = tid & 15;
  float acc[5] = {};
  for (int kc = 0; kc < NKC; ++kc) {
    if (kc) __syncthreads();
    #pragma unroll
    for (int i = 0; i < 16 * KCH / 256; ++i) {
      int e = tid + i * 256;
      int r = e / KCH, k = e - r * KCH;
      As[r * P + k] = A[(row0 + r) * Astride + kc * KCH + k];
    }
    #pragma unroll
    for (int i = 0; i < KCH * 80 / 256; ++i) {
      int e = tid + i * 256;
      int kr = e / 80, c = e - kr * 80;
      Wt[c * P + kr] = W[(kc * KCH + kr) * 80 + c];
    }
    __syncthreads();
    #pragma unroll 4
    for (int k4 = 0; k4 < KCH; k4 += 4) {
      float4 a = *(const float4*)&As[rr * P + k4];
      #pragma unroll
      for (int m = 0; m < 5; ++m) {
        float4 w = *(const float4*)&Wt[(c16 + 16 * m) * P + k4];
        acc[m] += a.x * w.x + a.y * w.y + a.z * w.z + a.w * w.w;
      }
    }
  }
  int row = row0 + rr;
  #pragma unroll
  for (int m = 0; m < 5; ++m) {
    int c = c16 + 16 * m;
    float v = acc[m];
    if (EPI == 4) v += bias[c];
    out[row * 80 + c] = v;
  }
}

// ---- cxf: conv+SiLU + x_proj + dt+softplus; xpT async-staged ----------------
__global__ __launch_bounds__(256) void cxf_k(const float* __restrict__ xz,
    fp cw, fp cb, fp xptl, fp dtw, fp dtb,
    float* __restrict__ xcf, float* __restrict__ xcbb,
    float* __restrict__ dbc2, float* __restrict__ dt2) {
  __shared__ float As[16 * 164];
  __shared__ float xpT[37 * 164];
  __shared__ float dbcl[16 * 40];
  int bi = blockIdx.x;
  int tc = bi % 50; int rem = bi / 50;
  int b = rem & 3, dir = rem >> 2;
  int t0 = tc * 16;
  int tid = threadIdx.x;
  stageN<1517>(xpT, xptl, tid);   // 6068 floats, async
  float* xco = dir ? xcbb : xcf;
  #pragma unroll
  for (int i = 0; i < 3; ++i) {
    int e = tid + i * 256;
    if (e < 640) {
      int ii = e / 40, d4 = (e - ii * 40) * 4;
      int t = t0 + ii;
      float4 acc = *(const float4*)&cb[d4];
      #pragma unroll
      for (int k = 0; k < 4; ++k) {
        int tt = t - 3 + k;
        if (tt >= 0) {
          int src = dir ? (T_ - 1 - tt) : tt;
          float4 xv = *(const float4*)&xz[(b * T_ + src) * 320 + d4];
          float4 wv = *(const float4*)&cw[k * DIN + d4];
          acc.x += wv.x * xv.x; acc.y += wv.y * xv.y;
          acc.z += wv.z * xv.z; acc.w += wv.w * xv.w;
        }
      }
      float4 o;
      o.x = acc.x / (1.f + __expf(-acc.x));
      o.y = acc.y / (1.f + __expf(-acc.y));
      o.z = acc.z / (1.f + __expf(-acc.z));
      o.w = acc.w / (1.f + __expf(-acc.w));
      *(float4*)&As[ii * 164 + d4] = o;
      *(float4*)&xco[(b * T_ + t) * DIN + d4] = o;
    }
  }
  __syncthreads();
  int rr = tid >> 4, c16 = tid & 15;
  int grow0 = dir * R_ + b * T_ + t0;
  {
    float a0 = 0.f, a1 = 0.f, a2 = 0.f;
    for (int k4 = 0; k4 < 160; k4 += 4) {
      float4 a = *(const float4*)&As[rr * 164 + k4];
      float4 w0 = *(const float4*)&xpT[c16 * 164 + k4];
      float4 w1 = *(const float4*)&xpT[(c16 + 16) * 164 + k4];
      a0 += a.x * w0.x + a.y * w0.y + a.z * w0.z + a.w * w0.w;
      a1 += a.x * w1.x + a.y * w1.y + a.z * w1.z + a.w * w1.w;
      if (c16 < 5) {
        float4 w2 = *(const float4*)&xpT[(c16 + 32) * 164 + k4];
        a2 += a.x * w2.x + a.y * w2.y + a.z * w2.z + a.w * w2.w;
      }
    }
    dbcl[rr * 40 + c16] = a0;
    dbcl[rr * 40 + c16 + 16] = a1;
    dbc2[(grow0 + rr) * 37 + c16] = a0;
    dbc2[(grow0 + rr) * 37 + c16 + 16] = a1;
    if (c16 < 5) {
      dbcl[rr * 40 + c16 + 32] = a2;
      dbc2[(grow0 + rr) * 37 + c16 + 32] = a2;
    }
  }
  __syncthreads();
  #pragma unroll
  for (int i = 0; i < 10; ++i) {
    int e = tid + i * 256;
    int ii = e / 160, d = e - ii * 160;
    float v = dtb[d];
    #pragma unroll
    for (int m = 0; m < 5; ++m) v += dbcl[ii * 40 + m] * dtw[m * DIN + d];
    v = fmaxf(v, 0.f) + __logf(1.f + __expf(-fabsf(v)));
    dt2[(grow0 + ii) * DIN + d] = v;
  }
}

// ---- scanA: per-chunk (prod, h_end) with h0=0; async 4B staging -------------
__global__ __launch_bounds__(256) void scanA_k(const float* __restrict__ dt2,
    const float* __restrict__ xcf, const float* __restrict__ xcbb,
    const float* __restrict__ dbc2, fp A_log,
    float* __restrict__ hend, float* __restrict__ pprod) {
  __shared__ float sdt[800], sX[800], sB[800];
  int bi = blockIdx.x;
  int cch = bi % NC; int rem = bi / NC;
  int dblk = rem % 10; rem /= 10;
  int b = rem % 4; int dir = rem / 4;
  int d0 = dblk * 16;
  int tid = threadIdx.x, dl = tid >> 4, n = tid & 15;
  int d = d0 + dl;
  const float* xc = dir ? xcbb : xcf;
  int rbase = dir * R_ + b * T_ + cch * LCH;
  int rloc0 = b * T_ + cch * LCH;
  int wv = tid >> 6, ln = tid & 63;
  #pragma unroll
  for (int i = 0; i < 4; ++i) {
    int cbase = i * 256 + wv * 64;
    int e = cbase + ln;
    if (e < 800) {
      int ii = e >> 4, jj = e & 15;
      int lo = __builtin_amdgcn_readfirstlane(cbase);
      g2l4(dt2 + (rbase + ii) * DIN + d0 + jj, sdt + lo);
      g2l4(xc + (rloc0 + ii) * DIN + d0 + jj, sX + lo);
      g2l4(dbc2 + (rbase + ii) * 37 + 5 + jj, sB + lo);
    }
  }
  float Areg = -__expf(A_log[d * NST + n]);
  __syncthreads();
  float h = 0.f, dts = 0.f;
  #pragma unroll 2
  for (int i = 0; i < LCH; ++i) {
    float dtv = sdt[i * 16 + dl];
    float aa = __expf(dtv * Areg);
    h = aa * h + dtv * sX[i * 16 + dl] * sB[i * 16 + n];
    dts += dtv;
  }
  hend[bi * 256 + tid] = h;
  pprod[bi * 256 + tid] = __expf(dts * Areg);
}

// ---- scanC: fused prefix + recompute + gated write; async 4B staging --------
__global__ __launch_bounds__(256) void scanC_k(const float* __restrict__ dt2,
    const float* __restrict__ dbc2, const float* __restrict__ xcf,
    const float* __restrict__ xcbb, const float* __restrict__ xz,
    fp A_log, fp Dp, const float* __restrict__ hend,
    const float* __restrict__ pprod, float* __restrict__ ygcat) {
  __shared__ float sdt[800], sX[800], sB[800], sC[800], sY[800];
  int bi = blockIdx.x;
  int cch = bi % NC; int rem = bi / NC;
  int dblk = rem % 10; rem /= 10;
  int b = rem % 4; int dir = rem / 4;
  int d0 = dblk * 16;
  int tid = threadIdx.x, dl = tid >> 4, n = tid & 15;
  int d = d0 + dl;
  const float* xc = dir ? xcbb : xcf;
  int rbase = dir * R_ + b * T_ + cch * LCH;
  int rloc0 = b * T_ + cch * LCH;
  int wv = tid >> 6, ln = tid & 63;
  #pragma unroll
  for (int i = 0; i < 4; ++i) {
    int cbase = i * 256 + wv * 64;
    int e = cbase + ln;
    if (e < 800) {
      int ii = e >> 4, jj = e & 15;
      int lo = __builtin_amdgcn_readfirstlane(cbase);
      g2l4(dt2 + (rbase + ii) * DIN + d0 + jj, sdt + lo);
      g2l4(xc + (rloc0 + ii) * DIN + d0 + jj, sX + lo);
      g2l4(dbc2 + (rbase + ii) * 37 + 5 + jj, sB + lo);
      g2l4(dbc2 + (rbase + ii) * 37 + 21 + jj, sC + lo);
    }
  }
  float Areg = -__expf(A_log[d * NST + n]);
  int sbase = (bi / NC) * (NC * 256) + tid;
  float h = 0.f;
  #pragma unroll
  for (int cc = 0; cc < NC; ++cc) {
    float p = pprod[sbase + cc * 256];
    float e = hend[sbase + cc * 256];
    if (cc < cch) h = p * h + e;
  }
  __syncthreads();
  for (int i = 0; i < LCH; ++i) {
    float dtv = sdt[i * 16 + dl];
    float a = __expf(dtv * Areg);
    h = a * h + dtv * sX[i * 16 + dl] * sB[i * 16 + n];
    float y = h * sC[i * 16 + n];
    y += __shfl_xor(y, 1);
    y += __shfl_xor(y, 2);
    y += __shfl_xor(y, 4);
    y += __shfl_xor(y, 8);
    if (n == 0) sY[i * 16 + dl] = y;
  }
  __syncthreads();
  for (int e = tid; e < LCH * 16; e += 256) {
    int i = e >> 4, jj = e & 15;
    int t = cch * LCH + i;
    float xcv = sX[i * 16 + jj];
    int orow = dir ? (b * T_ + (T_ - 1 - t)) : (b * T_ + t);
    float z = xz[orow * 320 + 160 + d0 + jj];
    float sg = 1.f / (1.f + __expf(-z));
    ygcat[orow * 320 + dir * 160 + d0 + jj] = (sY[i * 16 + jj] + xcv * Dp[d0 + jj]) * (z * sg);
  }
}

// ---- gof: out_proj(sum fwd/bwd) + in-block LN2 + ff1-half + GELU ------------
// grid (200, 2): blockIdx.y = ff1 half
__global__ __launch_bounds__(256, 2) void gof_k(const float* __restrict__ yg,
    fp wotp_l, fp w1pp_l, fp uv1, float* __restrict__ g1) {
  __shared__ float S[17120];
  float* Wt = S;             // [80][164]
  float* As = S + 13120;     // [16][164]
  float* sl = S + 15744;     // [16][84]
  float* ss = S + 17088;     // [32]
  int tid = threadIdx.x, row0 = blockIdx.x * 16, rr = tid >> 4, c16 = tid & 15;
  int h = blockIdx.y;
  stageN<3280>(Wt, wotp_l, tid);
  #pragma unroll
  for (int i = 0; i < 10; ++i) {
    int e = tid + i * 256; int r = e / 160, k = e - r * 160;
    As[r * 164 + k] = yg[(row0 + r) * 320 + k] + yg[(row0 + r) * 320 + 160 + k];
  }
  __syncthreads();
  {
    float acc[5] = {};
    #pragma unroll 4
    for (int k4 = 0; k4 < 160; k4 += 4) {
      float4 a = *(const float4*)&As[rr * 164 + k4];
      #pragma unroll
      for (int m = 0; m < 5; ++m) {
        float4 w = *(const float4*)&Wt[(c16 + 16 * m) * 164 + k4];
        acc[m] += a.x * w.x + a.y * w.y + a.z * w.z + a.w * w.w;
      }
    }
    float s = 0.f, q = 0.f;
    #pragma unroll
    for (int m = 0; m < 5; ++m) {
      float v = acc[m];
      sl[rr * 84 + c16 + 16 * m] = v;
      s += v; q += v * v;
    }
    s += __shfl_xor(s, 1); s += __shfl_xor(s, 2);
    s += __shfl_xor(s, 4); s += __shfl_xor(s, 8);
    q += __shfl_xor(q, 1); q += __shfl_xor(q, 2);
    q += __shfl_xor(q, 4); q += __shfl_xor(q, 8);
    if (c16 == 0) {
      float mu = s * 0.0125f;
      ss[rr * 2] = mu;
      ss[rr * 2 + 1] = rsqrtf(fmaxf(q * 0.0125f - mu * mu, 0.f) + 1e-5f);
    }
  }
  __syncthreads();
  stageN<3280>(Wt, w1pp_l + h * 13120, tid);
  __syncthreads();
  {
    float mu = ss[rr * 2], rs = ss[rr * 2 + 1];
    float a2[10] = {};
    for (int k = 0; k < 80; k += 4) {
      float4 av = *(const float4*)&sl[rr * 84 + k];
      #pragma unroll
      for (int m = 0; m < 10; ++m) {
        int c = c16 + 16 * m;
        a2[m] += av.x * Wt[k * 164 + c] + av.y * Wt[(k + 1) * 164 + c]
               + av.z * Wt[(k + 2) * 164 + c] + av.w * Wt[(k + 3) * 164 + c];
      }
    }
    #pragma unroll
    for (int m = 0; m < 10; ++m) {
      int c = h * 160 + c16 + 16 * m;
      float v = rs * a2[m] - mu * rs * uv1[c] + uv1[320 + c];
      v = 0.5f * v * (1.f + erff(v * 0.70710678118f));
      g1[(row0 + rr) * 320 + c] = v;
    }
  }
}

// ---- gfi: ff2 + bias + residual(xin->xout) + in-block LN1 + in_proj-half ----
// grid (200, 2): blockIdx.y = in_proj half; x ping-pong avoids RMW race
template<int LAST>
__global__ __launch_bounds__(256, 2) void gfi_k(const float* __restrict__ g1,
    fp w2tp_l, fp fb2, const float* __restrict__ xin, float* __restrict__ xout,
    fp wpnp_l, fp uvn, float* __restrict__ xz) {
  __shared__ float S[17120];
  float* Wt = S;             // [80][164]
  float* As = S + 13120;     // [16][164]
  float* xn = S + 15744;     // [16][84]
  float* ss = S + 17088;     // [32]
  int tid = threadIdx.x, row0 = blockIdx.x * 16, rr = tid >> 4, c16 = tid & 15;
  int h = blockIdx.y;
  float acc2[5] = {};
  for (int kc = 0; kc < 2; ++kc) {
    if (kc) __syncthreads();
    stageN<3280>(Wt, w2tp_l + kc * 13120, tid);
    #pragma unroll
    for (int i = 0; i < 10; ++i) {
      int e = tid + i * 256; int r = e / 160, k = e - r * 160;
      As[r * 164 + k] = g1[(row0 + r) * 320 + kc * 160 + k];
    }
    __syncthreads();
    #pragma unroll 4
    for (int k4 = 0; k4 < 160; k4 += 4) {
      float4 a = *(const float4*)&As[rr * 164 + k4];
      #pragma unroll
      for (int m = 0; m < 5; ++m) {
        float4 w = *(const float4*)&Wt[(c16 + 16 * m) * 164 + k4];
        acc2[m] += a.x * w.x + a.y * w.y + a.z * w.z + a.w * w.w;
      }
    }
  }
  {
    float s = 0.f, q = 0.f;
    #pragma unroll
    for (int m = 0; m < 5; ++m) {
      int c = c16 + 16 * m;
      float v = acc2[m] + fb2[c] + xin[(row0 + rr) * 80 + c];
      xout[(row0 + rr) * 80 + c] = v;   // both y-blocks write identical values
      xn[rr * 84 + c] = v;
      s += v; q += v * v;
    }
    if (!LAST) {
      s += __shfl_xor(s, 1); s += __shfl_xor(s, 2);
      s += __shfl_xor(s, 4); s += __shfl_xor(s, 8);
      q += __shfl_xor(q, 1); q += __shfl_xor(q, 2);
      q += __shfl_xor(q, 4); q += __shfl_xor(q, 8);
      if (c16 == 0) {
        float mu = s * 0.0125f;
        ss[rr * 2] = mu;
        ss[rr * 2 + 1] = rsqrtf(fmaxf(q * 0.0125f - mu * mu, 0.f) + 1e-5f);
      }
    }
  }
  if (!LAST) {
    __syncthreads();
    stageN<3280>(Wt, wpnp_l + h * 13120, tid);
    __syncthreads();
    float mu = ss[rr * 2], rs = ss[rr * 2 + 1];
    float a3[10] = {};
    for (int k = 0; k < 80; k += 4) {
      float4 av = *(const float4*)&xn[rr * 84 + k];
      #pragma unroll
      for (int m = 0; m < 10; ++m) {
        int c = c16 + 16 * m;
        a3[m] += av.x * Wt[k * 164 + c] + av.y * Wt[(k + 1) * 164 + c]
               + av.z * Wt[(k + 2) * 164 + c] + av.w * Wt[(k + 3) * 164 + c];
      }
    }
    #pragma unroll
    for (int m = 0; m < 10; ++m) {
      int c = h * 160 + c16 + 16 * m;
      xz[(row0 + rr) * 320 + c] = rs * a3[m] - mu * rs * uvn[c] + uvn[320 + c];
    }
  }
}

// ---- pooling: per-(b,c) mean/std over T -------------------------------------
__global__ __launch_bounds__(256) void stats_k(const float* __restrict__ x,
                                               float* __restrict__ meanv, float* __restrict__ stdv) {
  int bc = blockIdx.x; int b = bc / C_, c = bc % C_;
  __shared__ float sb[4];
  int tid = threadIdx.x;
  float v[4]; float s = 0.f;
  #pragma unroll
  for (int i = 0; i < 4; ++i) {
    int t = tid + i * 256;
    v[i] = (t < T_) ? x[(b * T_ + t) * C_ + c] : 0.f;
    s += v[i];
  }
  s = blockSum(s, sb);
  float mu = s * (1.f / T_);
  float q = 0.f;
  #pragma unroll
  for (int i = 0; i < 4; ++i) {
    int t = tid + i * 256;
    if (t < T_) { float dd = v[i] - mu; q += dd * dd; }
  }
  q = blockSum(q, sb);
  if (tid == 0) { meanv[bc] = mu; stdv[bc] = sqrtf(fmaxf(q * (1.f / T_), 1e-12f)); }
}

// ---- att1 pack --------------------------------------------------------------
__global__ __launch_bounds__(256) void prep_k(const float* __restrict__ meanv,
    const float* __restrict__ stdv, fp w1, fp ab1, fp g1p, fp b1p, fp m1p, fp v1p,
    float* __restrict__ pack) {
  int idx = blockIdx.x * 256 + threadIdx.x;
  if (idx < 512) {
    int b = idx / 128, dcol = idx % 128;
    float acc = ab1[dcol];
    for (int c = 0; c < C_; ++c) {
      acc += meanv[b * C_ + c] * w1[(C_ + c) * 128 + dcol];
      acc += stdv[b * C_ + c] * w1[(2 * C_ + c) * 128 + dcol];
    }
    pack[idx] = acc;
  } else if (idx < 640) {
    int dcol = idx - 512;
    float kv = g1p[dcol] * rsqrtf(v1p[dcol] + 1e-5f);
    pack[512 + dcol] = kv;
    pack[640 + dcol] = b1p[dcol] - m1p[dcol] * kv;
  }
}

// ---- softmax over T + weighted stats + bn2 ----------------------------------
__global__ __launch_bounds__(256) void pool_k(const float* __restrict__ x,
    const float* __restrict__ scores, fp g2, fp b2, fp m2, fp v2,
    float* __restrict__ pooledn) {
  int bc = blockIdx.x; int b = bc / C_, c = bc % C_;
  __shared__ float sb[4];
  int tid = threadIdx.x;
  float sv[4], xv[4];
  float mx = -1e30f;
  #pragma unroll
  for (int i = 0; i < 4; ++i) {
    int t = tid + i * 256;
    if (t < T_) { sv[i] = scores[(b * T_ + t) * C_ + c]; xv[i] = x[(b * T_ + t) * C_ + c]; }
    else { sv[i] = -1e30f; xv[i] = 0.f; }
    mx = fmaxf(mx, sv[i]);
  }
  mx = blockMax(mx, sb);
  float se = 0.f, sx = 0.f, sxx = 0.f;
  #pragma unroll
  for (int i = 0; i < 4; ++i) {
    float e = expf(sv[i] - mx);
    se += e; sx += e * xv[i]; sxx += e * xv[i] * xv[i];
  }
  se = blockSum(se, sb);
  sx = blockSum(sx, sb);
  sxx = blockSum(sxx, sb);
  if (tid == 0) {
    float mu = sx / se;
    float sg = sqrtf(fmaxf(sxx / se - mu * mu, 1e-12f));
    int j0 = c, j1 = C_ + c;
    pooledn[b * 160 + j0] = (mu - m2[j0]) * rsqrtf(v2[j0] + 1e-5f) * g2[j0] + b2[j0];
    pooledn[b * 160 + j1] = (sg - m2[j1]) * rsqrtf(v2[j1] + 1e-5f) * g2[j1] + b2[j1];
  }
}

// ---- final fc ---------------------------------------------------------------
__global__ __launch_bounds__(256) void fc_k(const float* __restrict__ pooledn, fp fw, fp fb,
                                            float* __restrict__ out) {
  int idx = blockIdx.x * 256 + threadIdx.x;
  if (idx >= 4 * 192) return;
  int b = idx / 192, e = idx % 192;
  float acc = fb[e];
  for (int i = 0; i < 160; ++i) acc += pooledn[b * 160 + i] * fw[i * 192 + e];
  out[idx] = acc;
}

extern "C" void kernel_launch(void* const* d_in, const int* in_sizes, int n_in,
                              void* d_out, int out_size, void* d_ws, size_t ws_size,
                              hipStream_t stream) {
  fp feat   = (fp)d_in[0];
  fp ln1_g  = (fp)d_in[1];  fp ln1_b  = (fp)d_in[2];
  fp in_proj= (fp)d_in[3];
  fp conv_w = (fp)d_in[4];  fp conv_b = (fp)d_in[5];
  fp x_proj = (fp)d_in[6];
  fp dt_w   = (fp)d_in[7];  fp dt_b   = (fp)d_in[8];
  fp A_log  = (fp)d_in[9];  fp Dp     = (fp)d_in[10];
  fp out_proj=(fp)d_in[11];
  fp ln2_g  = (fp)d_in[12]; fp ln2_b  = (fp)d_in[13];
  fp ff_w1  = (fp)d_in[14]; fp ff_b1  = (fp)d_in[15];
  fp ff_w2  = (fp)d_in[16]; fp ff_b2  = (fp)d_in[17];
  fp att_w1 = (fp)d_in[18]; fp att_b1 = (fp)d_in[19];
  fp bn1_g  = (fp)d_in[20]; fp bn1_b  = (fp)d_in[21];
  fp bn1_m  = (fp)d_in[22]; fp bn1_v  = (fp)d_in[23];
  fp att_w2 = (fp)d_in[24]; fp att_b2 = (fp)d_in[25];
  fp bn2_g  = (fp)d_in[26]; fp bn2_b  = (fp)d_in[27];
  fp bn2_m  = (fp)d_in[28]; fp bn2_v  = (fp)d_in[29];
  fp fc_w   = (fp)d_in[30]; fp fc_b   = (fp)d_in[31];

  float* ws   = (float*)d_ws;
  float* x    = ws;               // 256000
  float* xz   = ws + 256000;      // 1024000
  float* xcf  = ws + 1280000;     // 512000
  float* xcb  = ws + 1792000;     // 512000
  float* dbc2 = ws + 2304000;     // 236800
  float* dt2  = ws + 2540800;     // 1024000
  float* hend = ws + 3564800;     // 327680
  float* pprod= ws + 3892480;     // 327680
  float* ygcat= ws + 4220160;     // 1024000
  float* meanv= ws + 5244160;     // 320
  float* stdv = ws + 5244480;     // 320
  float* pack = ws + 5244800;     // 768
  float* pooledn = ws + 5245568;  // 640
  float* wp   = ws + 5246208;     // 614400
  float* uvb  = ws + 5860608;     // 15360
  float* mst_x= ws + 5875968;     // 6400
  float* xptp = ws + 5882368;     // 72816
  float* wotp = ws + 5955184;     // 157440
  float* w1pp = ws + 6112624;     // 314880
  float* w2tp = ws + 6427504;     // 314880
  float* wpnp = ws + 6742384;     // 314880
  float* x2   = ws + 7057264;     // 256000  (end 7313264 = 29.3 MiB)
  float* g1   = xz;               // alias: xz free after scanC
  float* a1b  = hend;             // alias: pooling only
  float* sc   = dt2;              // alias: pooling only
  float* xb[2] = { x, x2 };

  prepw_k<<<30, 256, 0, stream>>>(in_proj, ff_w1, ln1_g, ln1_b, ln2_g, ln2_b,
                                  ff_b1, wp, uvb);
  prepg_k<<<4305, 256, 0, stream>>>(out_proj, ff_w2, wp, wotp, w1pp, w2tp, wpnp);
  prepx_k<<<285, 256, 0, stream>>>(x_proj, xptp);
  cmn_k<<<320, 256, 0, stream>>>(feat, x);
  rstat_k<<<200, 256, 0, stream>>>(x, mst_x);
  gw_k<0><<<250, 256, 0, stream>>>(x, wp, uvb, mst_x, nullptr, xz, 320);

  for (int l = 0; l < 12; ++l) {
    cxf_k<<<400, 256, 0, stream>>>(xz, conv_w + l * 640, conv_b + l * 160,
                                   xptp + l * 6068, dt_w + l * 800, dt_b + l * 160,
                                   xcf, xcb, dbc2, dt2);
    scanA_k<<<1280, 256, 0, stream>>>(dt2, xcf, xcb, dbc2, A_log + l * 2560,
                                      hend, pprod);
    scanC_k<<<1280, 256, 0, stream>>>(dt2, dbc2, xcf, xcb, xz, A_log + l * 2560,
                                      Dp + l * 160, hend, pprod, ygcat);
    gof_k<<<dim3(200, 2), 256, 0, stream>>>(ygcat, wotp + l * 13120,
                                            w1pp + l * 26240,
                                            uvb + (2 * l + 1) * 640, g1);
    if (l < 11)
      gfi_k<0><<<dim3(200, 2), 256, 0, stream>>>(g1, w2tp + l * 26240,
                                                 ff_b2 + l * 80, xb[l & 1],
                                                 xb[(l + 1) & 1],
                                                 wpnp + l * 26240,
                                                 uvb + (2 * l + 2) * 640, xz);
    else
      gfi_k<1><<<dim3(200, 2), 256, 0, stream>>>(g1, w2tp + l * 26240,
                                                 ff_b2 + l * 80, xb[l & 1],
                                                 xb[(l + 1) & 1],
                                                 wpnp + l * 26240, uvb, xz);
  }

  stats_k<<<320, 256, 0, stream>>>(x, meanv, stdv);
  prep_k<<<3, 256, 0, stream>>>(meanv, stdv, att_w1, att_b1, bn1_g, bn1_b, bn1_m, bn1_v, pack);
  gw_k<3><<<100, 256, 0, stream>>>(x, att_w1, nullptr, nullptr, pack, a1b, 128);
  gc_k<4, 128, 1><<<200, 256, 0, stream>>>(a1b, att_w2, att_b2, sc, 128);
  pool_k<<<320, 256, 0, stream>>>(x, sc, bn2_g, bn2_b, bn2_m, bn2_v, pooledn);
  fc_k<<<3, 256, 0, stream>>>(pooledn, fc_w, fc_b, (float*)d_out);
}